// Round 1
// 2658.727 us; speedup vs baseline: 1.0540x; 1.0540x over previous
//
#include <hip/hip_runtime.h>
#include <hip/hip_bf16.h>
#include <stdint.h>

#define D_ 1024
#define S_ 2048
#define B_ 4
#define H_ 16
#define T_ 8192
#define E_ 8
#define CAP_ 2560
#define F_ 4096
#define FS_ 2048

typedef __attribute__((ext_vector_type(8))) short s8v;
typedef __attribute__((ext_vector_type(4))) float f4v;

#define GLL(gp, lp) __builtin_amdgcn_global_load_lds( \
    (const __attribute__((address_space(1))) unsigned int*)(gp), \
    (__attribute__((address_space(3))) unsigned int*)(lp), 16, 0, 0)

__device__ inline short f2bf(float f) {
    union { float f; unsigned u; } v; v.f = f;
    unsigned r = (v.u + 0x7fffu + ((v.u >> 16) & 1u)) >> 16;
    return (short)(r & 0xffffu);
}
__device__ inline float b2f(short h) {
    union { unsigned u; float f; } v; v.u = ((unsigned)(unsigned short)h) << 16; return v.f;
}
__device__ inline float gelu_f(float x) {
    return 0.5f * x * (1.0f + erff(x * 0.7071067811865475f));
}
__device__ inline f4v f4zero() { f4v z; z[0]=0.f; z[1]=0.f; z[2]=0.f; z[3]=0.f; return z; }

// ---------------- transpose + fp32->bf16 (single plane, MoE weights) ----------------
__global__ __launch_bounds__(256) void transcvt(const float* __restrict__ in,
                                                short* __restrict__ out, int R, int C)
{
    __shared__ float tile[32][33];
    const int tid = threadIdx.x;
    const int tx = tid & 31, ty = tid >> 5;
    const long long ib = (long long)blockIdx.z * R * C;
    const int r0 = blockIdx.y * 32, c0 = blockIdx.x * 32;
#pragma unroll
    for (int i = 0; i < 4; i++)
        tile[ty + i * 8][tx] = in[ib + (long long)(r0 + ty + i * 8) * C + c0 + tx];
    __syncthreads();
#pragma unroll
    for (int i = 0; i < 4; i++)
        out[ib + (long long)(c0 + ty + i * 8) * R + r0 + tx] = f2bf(tile[tx][ty + i * 8]);
}

// ---------------- transpose + hi/lo split (attention weights) ----------------
__global__ __launch_bounds__(256) void transcvt2(const float* __restrict__ in,
    short* __restrict__ oh, short* __restrict__ ol, int R, int C)
{
    __shared__ float tile[32][33];
    const int tid = threadIdx.x;
    const int tx = tid & 31, ty = tid >> 5;
    const int r0 = blockIdx.y * 32, c0 = blockIdx.x * 32;
#pragma unroll
    for (int i = 0; i < 4; i++)
        tile[ty + i * 8][tx] = in[(long long)(r0 + ty + i * 8) * C + c0 + tx];
    __syncthreads();
#pragma unroll
    for (int i = 0; i < 4; i++) {
        const float v = tile[tx][ty + i * 8];
        const short h = f2bf(v);
        const long long o = (long long)(c0 + ty + i * 8) * R + r0 + tx;
        oh[o] = h;
        ol[o] = f2bf(v - b2f(h));
    }
}

// ---------------- LN1: fp32 x -> hi/lo bf16 planes ----------------
__global__ __launch_bounds__(256) void ln1_split(const float* __restrict__ x,
    const float* __restrict__ g, const float* __restrict__ bta,
    short* __restrict__ xh, short* __restrict__ xl)
{
    const int t = blockIdx.x, tid = threadIdx.x;
    const float4 v = ((const float4*)(x + (long long)t * D_))[tid];
    float s1 = v.x + v.y + v.z + v.w;
    float s2 = v.x * v.x + v.y * v.y + v.z * v.z + v.w * v.w;
#pragma unroll
    for (int off = 32; off; off >>= 1) { s1 += __shfl_xor(s1, off, 64); s2 += __shfl_xor(s2, off, 64); }
    __shared__ float r1[4], r2[4];
    if ((tid & 63) == 0) { r1[tid >> 6] = s1; r2[tid >> 6] = s2; }
    __syncthreads();
    s1 = r1[0] + r1[1] + r1[2] + r1[3];
    s2 = r2[0] + r2[1] + r2[2] + r2[3];
    const float mu = s1 * (1.0f / D_);
    const float var = s2 * (1.0f / D_) - mu * mu;
    const float rs = rsqrtf(var + 1e-5f);
    const float4 gv = ((const float4*)g)[tid];
    const float4 bv = ((const float4*)bta)[tid];
    float xn[4];
    xn[0] = (v.x - mu) * rs * gv.x + bv.x;
    xn[1] = (v.y - mu) * rs * gv.y + bv.y;
    xn[2] = (v.z - mu) * rs * gv.z + bv.z;
    xn[3] = (v.w - mu) * rs * gv.w + bv.w;
    short4 hh, ll;
    hh.x = f2bf(xn[0]); ll.x = f2bf(xn[0] - b2f(hh.x));
    hh.y = f2bf(xn[1]); ll.y = f2bf(xn[1] - b2f(hh.y));
    hh.z = f2bf(xn[2]); ll.z = f2bf(xn[2] - b2f(hh.z));
    hh.w = f2bf(xn[3]); ll.w = f2bf(xn[3] - b2f(hh.w));
    ((short4*)(xh + (long long)t * D_))[tid] = hh;
    ((short4*)(xl + (long long)t * D_))[tid] = ll;
}

// ---------------- LN2 + router (fp32 logits, bf16 xn out) ----------------
__global__ __launch_bounds__(256) void ln2_router_kernel(const float* __restrict__ x,
    const float* __restrict__ g, const float* __restrict__ bta, const float* __restrict__ wr,
    short* __restrict__ xo, int* __restrict__ topi, float* __restrict__ gates)
{
    const int t = blockIdx.x, tid = threadIdx.x;
    const float4 v = ((const float4*)(x + (long long)t * D_))[tid];
    float s1 = v.x + v.y + v.z + v.w;
    float s2 = v.x * v.x + v.y * v.y + v.z * v.z + v.w * v.w;
#pragma unroll
    for (int off = 32; off; off >>= 1) { s1 += __shfl_xor(s1, off, 64); s2 += __shfl_xor(s2, off, 64); }
    __shared__ float r1[4], r2[4];
    if ((tid & 63) == 0) { r1[tid >> 6] = s1; r2[tid >> 6] = s2; }
    __syncthreads();
    s1 = r1[0] + r1[1] + r1[2] + r1[3];
    s2 = r2[0] + r2[1] + r2[2] + r2[3];
    const float mu = s1 * (1.0f / D_);
    const float var = s2 * (1.0f / D_) - mu * mu;
    const float rs = rsqrtf(var + 1e-5f);
    const float4 gv = ((const float4*)g)[tid];
    const float4 bv = ((const float4*)bta)[tid];
    float xn[4];
    xn[0] = (v.x - mu) * rs * gv.x + bv.x;
    xn[1] = (v.y - mu) * rs * gv.y + bv.y;
    xn[2] = (v.z - mu) * rs * gv.z + bv.z;
    xn[3] = (v.w - mu) * rs * gv.w + bv.w;
    short4 o;
    o.x = f2bf(xn[0]); o.y = f2bf(xn[1]); o.z = f2bf(xn[2]); o.w = f2bf(xn[3]);
    ((short4*)(xo + (long long)t * D_))[tid] = o;

    float a8[8] = {0, 0, 0, 0, 0, 0, 0, 0};
#pragma unroll
    for (int q = 0; q < 4; q++) {
        const int d = tid * 4 + q;
        const float4 w0 = ((const float4*)(wr + d * 8))[0];
        const float4 w1 = ((const float4*)(wr + d * 8))[1];
        a8[0] += xn[q] * w0.x; a8[1] += xn[q] * w0.y; a8[2] += xn[q] * w0.z; a8[3] += xn[q] * w0.w;
        a8[4] += xn[q] * w1.x; a8[5] += xn[q] * w1.y; a8[6] += xn[q] * w1.z; a8[7] += xn[q] * w1.w;
    }
    __shared__ float lred[32];
#pragma unroll
    for (int e = 0; e < 8; e++) {
        float vv = a8[e];
#pragma unroll
        for (int off = 32; off; off >>= 1) vv += __shfl_xor(vv, off, 64);
        if ((tid & 63) == 0) lred[(tid >> 6) * 8 + e] = vv;
    }
    __syncthreads();
    if (tid == 0) {
        float lg[8];
#pragma unroll
        for (int e = 0; e < 8; e++) lg[e] = lred[e] + lred[8 + e] + lred[16 + e] + lred[24 + e];
        int e0 = 0;
        for (int e = 1; e < 8; e++) if (lg[e] > lg[e0]) e0 = e;
        int e1 = (e0 == 0) ? 1 : 0;
        for (int e = 0; e < 8; e++) if (e != e0 && lg[e] > lg[e1]) e1 = e;
        const float mx = lg[e0];
        float den = 0.f;
        for (int e = 0; e < 8; e++) den += expf(lg[e] - mx);
        const float p0 = expf(lg[e0] - mx) / den;
        const float p1 = expf(lg[e1] - mx) / den;
        const float inv = 1.0f / (p0 + p1);
        topi[t * 2] = e0; topi[t * 2 + 1] = e1;
        gates[t * 2] = p0 * inv; gates[t * 2 + 1] = p1 * inv;
    }
}

// ---------------- slot-major capacity scan ----------------
__global__ __launch_bounds__(256) void route_scan(const int* __restrict__ topi,
    const float* __restrict__ gates, int* __restrict__ posc, float* __restrict__ wv)
{
    const int tid = threadIdx.x;
    const int w = tid >> 6, lane = tid & 63;
    __shared__ int wsum[4 * 8];
    int cnt[8] = {0, 0, 0, 0, 0, 0, 0, 0};
    const int base_r = tid * 64;
    for (int i = 0; i < 64; i++) {
        const int r = base_r + i;
        const int k = r >> 13, t = r & (T_ - 1);
        cnt[topi[t * 2 + k]]++;
    }
    int excl[8];
#pragma unroll
    for (int e = 0; e < 8; e++) {
        int x = cnt[e];
#pragma unroll
        for (int off = 1; off < 64; off <<= 1) {
            int y = __shfl_up(x, off, 64);
            if (lane >= off) x += y;
        }
        excl[e] = x - cnt[e];
        if (lane == 63) wsum[w * 8 + e] = x;
    }
    __syncthreads();
    int pos[8];
#pragma unroll
    for (int e = 0; e < 8; e++) {
        int s = 0;
        for (int ww = 0; ww < 4; ww++) if (ww < w) s += wsum[ww * 8 + e];
        pos[e] = s + excl[e];
    }
    for (int i = 0; i < 64; i++) {
        const int r = base_r + i;
        const int k = r >> 13, t = r & (T_ - 1);
        const int e = topi[t * 2 + k];
        const int p = pos[e]++;
        const bool keep = p < CAP_;
        posc[r] = keep ? p : -1;
        wv[r] = keep ? gates[t * 2 + k] : 0.0f;
    }
}

// ---------------- dispatch copy ----------------
__global__ __launch_bounds__(128) void dispatch_kernel(const short* __restrict__ xn2,
    const int* __restrict__ topi, const int* __restrict__ posc, short* __restrict__ disp)
{
    const int r = blockIdx.x;
    const int p = posc[r];
    if (p < 0) return;
    const int k = r >> 13, t = r & (T_ - 1);
    const int e = topi[t * 2 + k];
    const int tid = threadIdx.x;
    *(s8v*)&disp[((long long)e * CAP_ + p) * D_ + tid * 8] =
        *(const s8v*)&xn2[(long long)t * D_ + tid * 8];
}

// ---------------- combine ----------------
__global__ __launch_bounds__(256) void combine_kernel(const float* __restrict__ x1,
    const float* __restrict__ ys, const float* __restrict__ eo,
    const int* __restrict__ topi, const int* __restrict__ posc,
    const float* __restrict__ wv, float* __restrict__ out)
{
    const int t = blockIdx.x, tid = threadIdx.x;
    float4 a = *(const float4*)&x1[(long long)t * D_ + tid * 4];
    const float4 b = *(const float4*)&ys[(long long)t * D_ + tid * 4];
    a.x += b.x; a.y += b.y; a.z += b.z; a.w += b.w;
#pragma unroll
    for (int k = 0; k < 2; k++) {
        const int r = k * T_ + t;
        const int p = posc[r];
        if (p >= 0) {
            const int e = topi[t * 2 + k];
            const float wt = wv[r];
            const float4 c = *(const float4*)&eo[((long long)e * CAP_ + p) * D_ + tid * 4];
            a.x += wt * c.x; a.y += wt * c.y; a.z += wt * c.z; a.w += wt * c.w;
        }
    }
    *(float4*)&out[(long long)t * D_ + tid * 4] = a;
}

// ---------------- single-plane bf16 GEMM (MoE path) ----------------
// EPI: 1 = bias+gelu -> bf16 ; 2 = bias -> f32
template <int EPI>
__global__ __launch_bounds__(256) void gemm_bt(
    const short* __restrict__ A, const short* __restrict__ Bt,
    const float* __restrict__ bias, void* __restrict__ Cout, int M, int N, int K, int ldc)
{
    __shared__ __align__(16) short lA[128 * 32];
    __shared__ __align__(16) short lB[128 * 32];
    const int tid = threadIdx.x;
    const int wvi = tid >> 6, lane = tid & 63, lid = lane & 15, quad = lane >> 4;
    const int wm = wvi >> 1, wn = wvi & 1;
    const int mBase = blockIdx.y * 128, nBase = blockIdx.x * 128;
    f4v acc[4][4];
#pragma unroll
    for (int i = 0; i < 4; i++)
#pragma unroll
        for (int j = 0; j < 4; j++) acc[i][j] = f4zero();
    const long long aOff0 = (long long)(mBase + (tid >> 2)) * K + (tid & 3) * 8;
    const long long aOff1 = aOff0 + 64LL * K;
    const long long bOff0 = (long long)(nBase + (tid >> 2)) * K + (tid & 3) * 8;
    const long long bOff1 = bOff0 + 64LL * K;
    const int wofs = wvi << 9;
    for (int k0 = 0; k0 < K; k0 += 32) {
        __syncthreads();
        GLL(A + aOff0 + k0, &lA[wofs]);  GLL(A + aOff1 + k0, &lA[2048 + wofs]);
        GLL(Bt + bOff0 + k0, &lB[wofs]); GLL(Bt + bOff1 + k0, &lB[2048 + wofs]);
        __syncthreads();
        s8v af[4], bf[4];
#pragma unroll
        for (int i = 0; i < 4; i++)
            af[i] = *(const s8v*)&lA[(wm * 64 + i * 16 + lid) * 32 + quad * 8];
#pragma unroll
        for (int j = 0; j < 4; j++)
            bf[j] = *(const s8v*)&lB[(wn * 64 + j * 16 + lid) * 32 + quad * 8];
#pragma unroll
        for (int i = 0; i < 4; i++)
#pragma unroll
            for (int j = 0; j < 4; j++)
                acc[i][j] = __builtin_amdgcn_mfma_f32_16x16x32_bf16(af[i], bf[j], acc[i][j], 0, 0, 0);
    }
    const int mW = mBase + wm * 64 + quad * 4;
    const int nW = nBase + wn * 64 + lid;
#pragma unroll
    for (int j = 0; j < 4; j++) {
        const int n = nW + j * 16;
        const float bn = bias[n];
#pragma unroll
        for (int i = 0; i < 4; i++) {
            const int m = mW + i * 16;
#pragma unroll
            for (int r = 0; r < 4; r++) {
                float v = acc[i][j][r] + bn;
                if (EPI == 1) { v = gelu_f(v); ((short*)Cout)[(long long)(m + r) * ldc + n] = f2bf(v); }
                else          { ((float*)Cout)[(long long)(m + r) * ldc + n] = v; }
            }
        }
    }
}

// ---------------- split hi/lo GEMM: C = (Ah+Al) * (Bh+Bl)^T  (3-term) ----------------
// EPI: 0 = bias -> dual bf16 planes ; 1 = bias + resid -> f32
template <int EPI>
__global__ __launch_bounds__(256) void gemm_hl(
    const short* __restrict__ Ah, const short* __restrict__ Al,
    const short* __restrict__ Bh, const short* __restrict__ Bl,
    const float* __restrict__ bias, const float* __restrict__ resid,
    short* __restrict__ Ch, short* __restrict__ Cl, float* __restrict__ Cf,
    int M, int N, int K, int ldc)
{
    __shared__ __align__(16) short lAh[4096], lAl[4096], lBh[4096], lBl[4096];
    const int tid = threadIdx.x;
    const int wvi = tid >> 6, lane = tid & 63, lid = lane & 15, quad = lane >> 4;
    const int wm = wvi >> 1, wn = wvi & 1;
    const int mBase = blockIdx.y * 128, nBase = blockIdx.x * 128;
    f4v acc[4][4];
#pragma unroll
    for (int i = 0; i < 4; i++)
#pragma unroll
        for (int j = 0; j < 4; j++) acc[i][j] = f4zero();
    const long long aOff0 = (long long)(mBase + (tid >> 2)) * K + (tid & 3) * 8;
    const long long aOff1 = aOff0 + 64LL * K;
    const long long bOff0 = (long long)(nBase + (tid >> 2)) * K + (tid & 3) * 8;
    const long long bOff1 = bOff0 + 64LL * K;
    const int wofs = wvi << 9;
    for (int k0 = 0; k0 < K; k0 += 32) {
        __syncthreads();
        GLL(Ah + aOff0 + k0, &lAh[wofs]);  GLL(Ah + aOff1 + k0, &lAh[2048 + wofs]);
        GLL(Al + aOff0 + k0, &lAl[wofs]);  GLL(Al + aOff1 + k0, &lAl[2048 + wofs]);
        GLL(Bh + bOff0 + k0, &lBh[wofs]);  GLL(Bh + bOff1 + k0, &lBh[2048 + wofs]);
        GLL(Bl + bOff0 + k0, &lBl[wofs]);  GLL(Bl + bOff1 + k0, &lBl[2048 + wofs]);
        __syncthreads();
        s8v ah[4], al[4], bh[4], bl[4];
#pragma unroll
        for (int i = 0; i < 4; i++) {
            const int ro = (wm * 64 + i * 16 + lid) * 32 + quad * 8;
            ah[i] = *(const s8v*)&lAh[ro];
            al[i] = *(const s8v*)&lAl[ro];
        }
#pragma unroll
        for (int j = 0; j < 4; j++) {
            const int ro = (wn * 64 + j * 16 + lid) * 32 + quad * 8;
            bh[j] = *(const s8v*)&lBh[ro];
            bl[j] = *(const s8v*)&lBl[ro];
        }
#pragma unroll
        for (int i = 0; i < 4; i++)
#pragma unroll
            for (int j = 0; j < 4; j++) {
                acc[i][j] = __builtin_amdgcn_mfma_f32_16x16x32_bf16(ah[i], bh[j], acc[i][j], 0, 0, 0);
                acc[i][j] = __builtin_amdgcn_mfma_f32_16x16x32_bf16(ah[i], bl[j], acc[i][j], 0, 0, 0);
                acc[i][j] = __builtin_amdgcn_mfma_f32_16x16x32_bf16(al[i], bh[j], acc[i][j], 0, 0, 0);
            }
    }
    const int mW = mBase + wm * 64 + quad * 4;
    const int nW = nBase + wn * 64 + lid;
#pragma unroll
    for (int j = 0; j < 4; j++) {
        const int n = nW + j * 16;
        const float bn = bias[n];
#pragma unroll
        for (int i = 0; i < 4; i++) {
            const int m = mW + i * 16;
#pragma unroll
            for (int r = 0; r < 4; r++) {
                const float v = acc[i][j][r] + bn;
                const long long o = (long long)(m + r) * ldc + n;
                if (EPI == 0) {
                    const short h = f2bf(v);
                    Ch[o] = h;
                    Cl[o] = f2bf(v - b2f(h));
                } else {
                    Cf[o] = v + resid[o];
                }
            }
        }
    }
}

// ---------------- flash attention, split hi/lo ----------------
// V-transpose LDS tile uses an XOR swizzle keyed on (row>>3)&3 to kill the
// 16-way bank conflict of the column-scatter store:
//   store: lVt[row][srow ^ ((row>>3 & 3)<<3)]   (row = d index, srow = k index)
//   read : 16B at col ((quad ^ ((d>>3)&3)) << 3)  -- stays b128-aligned.
// At fixed jj the store previously hit 4 banks with 64 lanes (160*sgrp = 0 mod 32);
// swizzled it spreads to 16 banks with dword merging -> ~2-way (free, m136).
__global__ __launch_bounds__(256) void flash_attn_hl(const short* __restrict__ qkvh,
    const short* __restrict__ qkvl, const unsigned char* __restrict__ mask,
    short* __restrict__ attnh, short* __restrict__ attnl)
{
    __shared__ __align__(16) short lKh[32 * 72], lKl[32 * 72];
    __shared__ __align__(16) short lVth[64 * 40], lVtl[64 * 40];
    __shared__ __align__(16) short lPh[4 * 16 * 40], lPl[4 * 16 * 40];
    const int tid = threadIdx.x;
    const int w = tid >> 6, lane = tid & 63, lid = lane & 15, quad = lane >> 4;
    const int bh = blockIdx.y;
    const int b = bh >> 4, h = bh & 15;
    const int q0row = blockIdx.x * 64 + w * 16;

    const long long rowQ = (long long)(b * S_ + q0row + lid) * 3072 + h * 64;
    const s8v qh0 = *(const s8v*)&qkvh[rowQ + quad * 8];
    const s8v qh1 = *(const s8v*)&qkvh[rowQ + 32 + quad * 8];
    const s8v ql0 = *(const s8v*)&qkvl[rowQ + quad * 8];
    const s8v ql1 = *(const s8v*)&qkvl[rowQ + 32 + quad * 8];

    float m_run[4], l_run[4];
    f4v o[4];
#pragma unroll
    for (int r = 0; r < 4; r++) { m_run[r] = -1e30f; l_run[r] = 0.0f; }
#pragma unroll
    for (int dt = 0; dt < 4; dt++) o[dt] = f4zero();

    const unsigned char* mrow = mask + b * S_;
    const int srow = tid >> 3, sgrp = tid & 7;

    for (int c0 = 0; c0 < S_; c0 += 32) {
        __syncthreads();
        {
            const long long gk = (long long)(b * S_ + c0 + srow) * 3072 + 1024 + h * 64 + sgrp * 8;
            *(s8v*)&lKh[srow * 72 + sgrp * 8] = *(const s8v*)&qkvh[gk];
            *(s8v*)&lKl[srow * 72 + sgrp * 8] = *(const s8v*)&qkvl[gk];
            const long long gv = (long long)(b * S_ + c0 + srow) * 3072 + 2048 + h * 64 + sgrp * 8;
            const s8v vh = *(const s8v*)&qkvh[gv];
            const s8v vl = *(const s8v*)&qkvl[gv];
            const int vcol = srow ^ ((sgrp & 3) << 3);   // XOR-swizzled k-column
#pragma unroll
            for (int jj = 0; jj < 8; jj++) {
                lVth[(sgrp * 8 + jj) * 40 + vcol] = vh[jj];
                lVtl[(sgrp * 8 + jj) * 40 + vcol] = vl[jj];
            }
        }
        __syncthreads();

        f4v s0 = f4zero(), s1 = f4zero();
        {
            const int r0 = lid * 72 + quad * 8;
            const s8v kh0a = *(const s8v*)&lKh[r0];
            const s8v kh0b = *(const s8v*)&lKh[r0 + 32];
            const s8v kl0a = *(const s8v*)&lKl[r0];
            const s8v kl0b = *(const s8v*)&lKl[r0 + 32];
            s0 = __builtin_amdgcn_mfma_f32_16x16x32_bf16(qh0, kh0a, s0, 0, 0, 0);
            s0 = __builtin_amdgcn_mfma_f32_16x16x32_bf16(qh1, kh0b, s0, 0, 0, 0);
            s0 = __builtin_amdgcn_mfma_f32_16x16x32_bf16(qh0, kl0a, s0, 0, 0, 0);
            s0 = __builtin_amdgcn_mfma_f32_16x16x32_bf16(qh1, kl0b, s0, 0, 0, 0);
            s0 = __builtin_amdgcn_mfma_f32_16x16x32_bf16(ql0, kh0a, s0, 0, 0, 0);
            s0 = __builtin_amdgcn_mfma_f32_16x16x32_bf16(ql1, kh0b, s0, 0, 0, 0);
            const int r1i = (16 + lid) * 72 + quad * 8;
            const s8v kh1a = *(const s8v*)&lKh[r1i];
            const s8v kh1b = *(const s8v*)&lKh[r1i + 32];
            const s8v kl1a = *(const s8v*)&lKl[r1i];
            const s8v kl1b = *(const s8v*)&lKl[r1i + 32];
            s1 = __builtin_amdgcn_mfma_f32_16x16x32_bf16(qh0, kh1a, s1, 0, 0, 0);
            s1 = __builtin_amdgcn_mfma_f32_16x16x32_bf16(qh1, kh1b, s1, 0, 0, 0);
            s1 = __builtin_amdgcn_mfma_f32_16x16x32_bf16(qh0, kl1a, s1, 0, 0, 0);
            s1 = __builtin_amdgcn_mfma_f32_16x16x32_bf16(qh1, kl1b, s1, 0, 0, 0);
            s1 = __builtin_amdgcn_mfma_f32_16x16x32_bf16(ql0, kh1a, s1, 0, 0, 0);
            s1 = __builtin_amdgcn_mfma_f32_16x16x32_bf16(ql1, kh1b, s1, 0, 0, 0);
        }
        const bool mk0 = mrow[c0 + lid] != 0;
        const bool mk1 = mrow[c0 + 16 + lid] != 0;
        float p0[4], p1[4];
#pragma unroll
        for (int r = 0; r < 4; r++) {
            p0[r] = mk0 ? -1e30f : s0[r] * 0.125f;
            p1[r] = mk1 ? -1e30f : s1[r] * 0.125f;
        }
        float mc[4];
#pragma unroll
        for (int r = 0; r < 4; r++) mc[r] = fmaxf(p0[r], p1[r]);
#pragma unroll
        for (int off = 1; off < 16; off <<= 1)
#pragma unroll
            for (int r = 0; r < 4; r++) mc[r] = fmaxf(mc[r], __shfl_xor(mc[r], off, 64));
        float alpha[4], rsum[4];
#pragma unroll
        for (int r = 0; r < 4; r++) {
            const float mn = fmaxf(m_run[r], mc[r]);
            alpha[r] = __expf(m_run[r] - mn);
            m_run[r] = mn;
            p0[r] = __expf(p0[r] - mn);
            p1[r] = __expf(p1[r] - mn);
            rsum[r] = p0[r] + p1[r];
        }
#pragma unroll
        for (int off = 1; off < 16; off <<= 1)
#pragma unroll
            for (int r = 0; r < 4; r++) rsum[r] += __shfl_xor(rsum[r], off, 64);
#pragma unroll
        for (int r = 0; r < 4; r++) l_run[r] = l_run[r] * alpha[r] + rsum[r];
#pragma unroll
        for (int dt = 0; dt < 4; dt++)
#pragma unroll
            for (int r = 0; r < 4; r++) o[dt][r] *= alpha[r];
#pragma unroll
        for (int r = 0; r < 4; r++) {
            const int o0 = w * 640 + (quad * 4 + r) * 40 + lid;
            const short h0 = f2bf(p0[r]);
            const short h1 = f2bf(p1[r]);
            lPh[o0] = h0;      lPl[o0] = f2bf(p0[r] - b2f(h0));
            lPh[o0 + 16] = h1; lPl[o0 + 16] = f2bf(p1[r] - b2f(h1));
        }
        __syncthreads();
        const s8v pah = *(const s8v*)&lPh[w * 640 + lid * 40 + quad * 8];
        const s8v pal = *(const s8v*)&lPl[w * 640 + lid * 40 + quad * 8];
#pragma unroll
        for (int dt = 0; dt < 4; dt++) {
            const int d = dt * 16 + lid;
            const int x3 = (dt * 2 + (lid >> 3)) & 3;          // (d>>3) & 3
            const int ro = d * 40 + ((quad ^ x3) << 3);        // de-swizzled b128 read
            const s8v bvh = *(const s8v*)&lVth[ro];
            const s8v bvl = *(const s8v*)&lVtl[ro];
            o[dt] = __builtin_amdgcn_mfma_f32_16x16x32_bf16(pah, bvh, o[dt], 0, 0, 0);
            o[dt] = __builtin_amdgcn_mfma_f32_16x16x32_bf16(pah, bvl, o[dt], 0, 0, 0);
            o[dt] = __builtin_amdgcn_mfma_f32_16x16x32_bf16(pal, bvh, o[dt], 0, 0, 0);
        }
    }
#pragma unroll
    for (int dt = 0; dt < 4; dt++)
#pragma unroll
        for (int r = 0; r < 4; r++) {
            const int m = q0row + quad * 4 + r;
            const float v = o[dt][r] / l_run[r];
            const long long idx = (long long)(b * S_ + m) * D_ + h * 64 + dt * 16 + lid;
            const short hh = f2bf(v);
            attnh[idx] = hh;
            attnl[idx] = f2bf(v - b2f(hh));
        }
}

// ---------------- workspace layout (bytes) ----------------
constexpr long long SZ_DD2   = (long long)D_ * D_ * 2;
constexpr long long OFF_WQKVH = 0;
constexpr long long OFF_WQKVL = OFF_WQKVH + 3 * SZ_DD2;
constexpr long long OFF_WOH   = OFF_WQKVL + 3 * SZ_DD2;
constexpr long long OFF_WOL   = OFF_WOH + SZ_DD2;
constexpr long long OFF_W1T   = OFF_WOL + SZ_DD2;
constexpr long long OFF_W2T   = OFF_W1T + (long long)E_ * F_ * D_ * 2;
constexpr long long OFF_WS1T  = OFF_W2T + (long long)E_ * D_ * F_ * 2;
constexpr long long OFF_WS2T  = OFF_WS1T + (long long)FS_ * D_ * 2;
constexpr long long OFF_X1    = OFF_WS2T + (long long)D_ * FS_ * 2;
constexpr long long OFF_XN2   = OFF_X1 + (long long)T_ * D_ * 4;
constexpr long long OFF_TOPI  = OFF_XN2 + (long long)T_ * D_ * 2;
constexpr long long OFF_GATES = OFF_TOPI + (long long)T_ * 2 * 4;
constexpr long long OFF_POSC  = OFF_GATES + (long long)T_ * 2 * 4;
constexpr long long OFF_WVAL  = OFF_POSC + (long long)2 * T_ * 4;
constexpr long long ZONE      = OFF_WVAL + (long long)2 * T_ * 4;
// attention phase
constexpr long long OFF_XH1   = ZONE;
constexpr long long OFF_XL1   = OFF_XH1 + (long long)T_ * D_ * 2;
constexpr long long OFF_QKVH  = OFF_XL1 + (long long)T_ * D_ * 2;
constexpr long long OFF_QKVL  = OFF_QKVH + (long long)T_ * 3 * D_ * 2;
constexpr long long OFF_ATTNH = OFF_QKVL + (long long)T_ * 3 * D_ * 2;
constexpr long long OFF_ATTNL = OFF_ATTNH + (long long)T_ * D_ * 2;
// MoE phase (reuses attention zone)
constexpr long long OFF_DISP  = ZONE;
constexpr long long OFF_H     = OFF_DISP + (long long)E_ * CAP_ * D_ * 2;
constexpr long long OFF_EO    = OFF_H + (long long)CAP_ * F_ * 2;
constexpr long long OFF_YS    = OFF_EO + (long long)E_ * CAP_ * D_ * 4;
constexpr long long OFF_HS    = ZONE;  // after experts (disp dead)

extern "C" void kernel_launch(void* const* d_in, const int* in_sizes, int n_in,
                              void* d_out, int out_size, void* d_ws, size_t ws_size,
                              hipStream_t stream)
{
    (void)in_sizes; (void)n_in; (void)out_size; (void)ws_size;
    const float* x       = (const float*)d_in[0];
    const unsigned char* mask = (const unsigned char*)d_in[1];
    const float* ln1g    = (const float*)d_in[2];
    const float* ln1b    = (const float*)d_in[3];
    const float* wq      = (const float*)d_in[4];
    const float* bq      = (const float*)d_in[5];
    const float* wk      = (const float*)d_in[6];
    const float* bk      = (const float*)d_in[7];
    const float* wvp     = (const float*)d_in[8];
    const float* bvv     = (const float*)d_in[9];
    const float* wo      = (const float*)d_in[10];
    const float* bo      = (const float*)d_in[11];
    const float* ln2g    = (const float*)d_in[12];
    const float* ln2b    = (const float*)d_in[13];
    const float* wrouter = (const float*)d_in[14];
    const float* w1      = (const float*)d_in[15];
    const float* b1      = (const float*)d_in[16];
    const float* w2      = (const float*)d_in[17];
    const float* b2      = (const float*)d_in[18];
    const float* ws1     = (const float*)d_in[19];
    const float* bs1     = (const float*)d_in[20];
    const float* ws2     = (const float*)d_in[21];
    const float* bs2     = (const float*)d_in[22];
    float* out = (float*)d_out;
    char* ws = (char*)d_ws;

    short* wqkvh = (short*)(ws + OFF_WQKVH);
    short* wqkvl = (short*)(ws + OFF_WQKVL);
    short* woh   = (short*)(ws + OFF_WOH);
    short* wol   = (short*)(ws + OFF_WOL);
    short* w1T   = (short*)(ws + OFF_W1T);
    short* w2T   = (short*)(ws + OFF_W2T);
    short* ws1T  = (short*)(ws + OFF_WS1T);
    short* ws2T  = (short*)(ws + OFF_WS2T);
    float* x1    = (float*)(ws + OFF_X1);
    short* xn2   = (short*)(ws + OFF_XN2);
    int*   topi  = (int*)(ws + OFF_TOPI);
    float* gates = (float*)(ws + OFF_GATES);
    int*   posc  = (int*)(ws + OFF_POSC);
    float* wval  = (float*)(ws + OFF_WVAL);
    short* xh1   = (short*)(ws + OFF_XH1);
    short* xl1   = (short*)(ws + OFF_XL1);
    short* qkvh  = (short*)(ws + OFF_QKVH);
    short* qkvl  = (short*)(ws + OFF_QKVL);
    short* attnh = (short*)(ws + OFF_ATTNH);
    short* attnl = (short*)(ws + OFF_ATTNL);
    short* disp  = (short*)(ws + OFF_DISP);
    short* hbuf  = (short*)(ws + OFF_H);
    float* eo    = (float*)(ws + OFF_EO);
    short* hs    = (short*)(ws + OFF_HS);
    float* ysb   = (float*)(ws + OFF_YS);

    const dim3 tb(256);
    transcvt2<<<dim3(32, 32), tb, 0, stream>>>(wq,  wqkvh,               wqkvl,               1024, 1024);
    transcvt2<<<dim3(32, 32), tb, 0, stream>>>(wk,  wqkvh + 1024 * 1024, wqkvl + 1024 * 1024, 1024, 1024);
    transcvt2<<<dim3(32, 32), tb, 0, stream>>>(wvp, wqkvh + 2 * 1024 * 1024, wqkvl + 2 * 1024 * 1024, 1024, 1024);
    transcvt2<<<dim3(32, 32), tb, 0, stream>>>(wo,  woh, wol, 1024, 1024);
    transcvt<<<dim3(128, 32, 8), tb, 0, stream>>>(w1, w1T, 1024, 4096);
    transcvt<<<dim3(32, 128, 8), tb, 0, stream>>>(w2, w2T, 4096, 1024);
    transcvt<<<dim3(64, 32, 1), tb, 0, stream>>>(ws1, ws1T, 1024, 2048);
    transcvt<<<dim3(32, 64, 1), tb, 0, stream>>>(ws2, ws2T, 2048, 1024);

    ln1_split<<<T_, 256, 0, stream>>>(x, ln1g, ln1b, xh1, xl1);

    gemm_hl<0><<<dim3(8, 64), 256, 0, stream>>>(xh1, xl1, wqkvh, wqkvl,
        bq, nullptr, qkvh, qkvl, nullptr, T_, 1024, 1024, 3072);
    gemm_hl<0><<<dim3(8, 64), 256, 0, stream>>>(xh1, xl1, wqkvh + 1024 * 1024, wqkvl + 1024 * 1024,
        bk, nullptr, qkvh + 1024, qkvl + 1024, nullptr, T_, 1024, 1024, 3072);
    gemm_hl<0><<<dim3(8, 64), 256, 0, stream>>>(xh1, xl1, wqkvh + 2 * 1024 * 1024, wqkvl + 2 * 1024 * 1024,
        bvv, nullptr, qkvh + 2048, qkvl + 2048, nullptr, T_, 1024, 1024, 3072);

    flash_attn_hl<<<dim3(32, 64), 256, 0, stream>>>(qkvh, qkvl, mask, attnh, attnl);

    gemm_hl<1><<<dim3(8, 64), 256, 0, stream>>>(attnh, attnl, woh, wol,
        bo, x, nullptr, nullptr, x1, T_, 1024, 1024, 1024);

    ln2_router_kernel<<<T_, 256, 0, stream>>>(x1, ln2g, ln2b, wrouter, xn2, topi, gates);
    route_scan<<<1, 256, 0, stream>>>(topi, gates, posc, wval);
    dispatch_kernel<<<2 * T_, 128, 0, stream>>>(xn2, topi, posc, disp);

    for (int e = 0; e < E_; e++) {
        gemm_bt<1><<<dim3(32, 20), 256, 0, stream>>>(disp + (long long)e * CAP_ * D_,
            w1T + (long long)e * F_ * D_, b1 + e * F_, hbuf, CAP_, F_, 1024, F_);
        gemm_bt<2><<<dim3(8, 20), 256, 0, stream>>>(hbuf,
            w2T + (long long)e * D_ * F_, b2 + e * D_, eo + (long long)e * CAP_ * D_,
            CAP_, 1024, F_, 1024);
    }

    gemm_bt<1><<<dim3(16, 64), 256, 0, stream>>>(xn2, ws1T, bs1, hs, T_, FS_, 1024, FS_);
    gemm_bt<2><<<dim3(8, 64), 256, 0, stream>>>(hs, ws2T, bs2, ysb, T_, 1024, FS_, 1024);

    combine_kernel<<<T_, 256, 0, stream>>>(x1, ysb, eo, topi, posc, wval, out);
}

// Round 2
// 2020.662 us; speedup vs baseline: 1.3868x; 1.3158x over previous
//
#include <hip/hip_runtime.h>
#include <hip/hip_bf16.h>
#include <stdint.h>

#define D_ 1024
#define S_ 2048
#define B_ 4
#define H_ 16
#define T_ 8192
#define E_ 8
#define CAP_ 2560
#define F_ 4096
#define FS_ 2048

typedef __attribute__((ext_vector_type(8))) short s8v;
typedef __attribute__((ext_vector_type(4))) float f4v;

#define GLL(gp, lp) __builtin_amdgcn_global_load_lds( \
    (const __attribute__((address_space(1))) unsigned int*)(gp), \
    (__attribute__((address_space(3))) unsigned int*)(lp), 16, 0, 0)

__device__ inline short f2bf(float f) {
    union { float f; unsigned u; } v; v.f = f;
    unsigned r = (v.u + 0x7fffu + ((v.u >> 16) & 1u)) >> 16;
    return (short)(r & 0xffffu);
}
__device__ inline float b2f(short h) {
    union { unsigned u; float f; } v; v.u = ((unsigned)(unsigned short)h) << 16; return v.f;
}
__device__ inline float gelu_f(float x) {
    return 0.5f * x * (1.0f + erff(x * 0.7071067811865475f));
}
__device__ inline f4v f4zero() { f4v z; z[0]=0.f; z[1]=0.f; z[2]=0.f; z[3]=0.f; return z; }

// ---------------- transpose + fp32->bf16 (single plane, MoE weights) ----------------
__global__ __launch_bounds__(256) void transcvt(const float* __restrict__ in,
                                                short* __restrict__ out, int R, int C)
{
    __shared__ float tile[32][33];
    const int tid = threadIdx.x;
    const int tx = tid & 31, ty = tid >> 5;
    const long long ib = (long long)blockIdx.z * R * C;
    const int r0 = blockIdx.y * 32, c0 = blockIdx.x * 32;
#pragma unroll
    for (int i = 0; i < 4; i++)
        tile[ty + i * 8][tx] = in[ib + (long long)(r0 + ty + i * 8) * C + c0 + tx];
    __syncthreads();
#pragma unroll
    for (int i = 0; i < 4; i++)
        out[ib + (long long)(c0 + ty + i * 8) * R + r0 + tx] = f2bf(tile[tx][ty + i * 8]);
}

// ---------------- transpose + hi/lo split (attention weights) ----------------
__global__ __launch_bounds__(256) void transcvt2(const float* __restrict__ in,
    short* __restrict__ oh, short* __restrict__ ol, int R, int C)
{
    __shared__ float tile[32][33];
    const int tid = threadIdx.x;
    const int tx = tid & 31, ty = tid >> 5;
    const int r0 = blockIdx.y * 32, c0 = blockIdx.x * 32;
#pragma unroll
    for (int i = 0; i < 4; i++)
        tile[ty + i * 8][tx] = in[(long long)(r0 + ty + i * 8) * C + c0 + tx];
    __syncthreads();
#pragma unroll
    for (int i = 0; i < 4; i++) {
        const float v = tile[tx][ty + i * 8];
        const short h = f2bf(v);
        const long long o = (long long)(c0 + ty + i * 8) * R + r0 + tx;
        oh[o] = h;
        ol[o] = f2bf(v - b2f(h));
    }
}

// ---------------- LN1: fp32 x -> hi/lo bf16 planes ----------------
__global__ __launch_bounds__(256) void ln1_split(const float* __restrict__ x,
    const float* __restrict__ g, const float* __restrict__ bta,
    short* __restrict__ xh, short* __restrict__ xl)
{
    const int t = blockIdx.x, tid = threadIdx.x;
    const float4 v = ((const float4*)(x + (long long)t * D_))[tid];
    float s1 = v.x + v.y + v.z + v.w;
    float s2 = v.x * v.x + v.y * v.y + v.z * v.z + v.w * v.w;
#pragma unroll
    for (int off = 32; off; off >>= 1) { s1 += __shfl_xor(s1, off, 64); s2 += __shfl_xor(s2, off, 64); }
    __shared__ float r1[4], r2[4];
    if ((tid & 63) == 0) { r1[tid >> 6] = s1; r2[tid >> 6] = s2; }
    __syncthreads();
    s1 = r1[0] + r1[1] + r1[2] + r1[3];
    s2 = r2[0] + r2[1] + r2[2] + r2[3];
    const float mu = s1 * (1.0f / D_);
    const float var = s2 * (1.0f / D_) - mu * mu;
    const float rs = rsqrtf(var + 1e-5f);
    const float4 gv = ((const float4*)g)[tid];
    const float4 bv = ((const float4*)bta)[tid];
    float xn[4];
    xn[0] = (v.x - mu) * rs * gv.x + bv.x;
    xn[1] = (v.y - mu) * rs * gv.y + bv.y;
    xn[2] = (v.z - mu) * rs * gv.z + bv.z;
    xn[3] = (v.w - mu) * rs * gv.w + bv.w;
    short4 hh, ll;
    hh.x = f2bf(xn[0]); ll.x = f2bf(xn[0] - b2f(hh.x));
    hh.y = f2bf(xn[1]); ll.y = f2bf(xn[1] - b2f(hh.y));
    hh.z = f2bf(xn[2]); ll.z = f2bf(xn[2] - b2f(hh.z));
    hh.w = f2bf(xn[3]); ll.w = f2bf(xn[3] - b2f(hh.w));
    ((short4*)(xh + (long long)t * D_))[tid] = hh;
    ((short4*)(xl + (long long)t * D_))[tid] = ll;
}

// ---------------- LN2 + router (fp32 logits, bf16 xn out) ----------------
__global__ __launch_bounds__(256) void ln2_router_kernel(const float* __restrict__ x,
    const float* __restrict__ g, const float* __restrict__ bta, const float* __restrict__ wr,
    short* __restrict__ xo, int* __restrict__ topi, float* __restrict__ gates)
{
    const int t = blockIdx.x, tid = threadIdx.x;
    const float4 v = ((const float4*)(x + (long long)t * D_))[tid];
    float s1 = v.x + v.y + v.z + v.w;
    float s2 = v.x * v.x + v.y * v.y + v.z * v.z + v.w * v.w;
#pragma unroll
    for (int off = 32; off; off >>= 1) { s1 += __shfl_xor(s1, off, 64); s2 += __shfl_xor(s2, off, 64); }
    __shared__ float r1[4], r2[4];
    if ((tid & 63) == 0) { r1[tid >> 6] = s1; r2[tid >> 6] = s2; }
    __syncthreads();
    s1 = r1[0] + r1[1] + r1[2] + r1[3];
    s2 = r2[0] + r2[1] + r2[2] + r2[3];
    const float mu = s1 * (1.0f / D_);
    const float var = s2 * (1.0f / D_) - mu * mu;
    const float rs = rsqrtf(var + 1e-5f);
    const float4 gv = ((const float4*)g)[tid];
    const float4 bv = ((const float4*)bta)[tid];
    float xn[4];
    xn[0] = (v.x - mu) * rs * gv.x + bv.x;
    xn[1] = (v.y - mu) * rs * gv.y + bv.y;
    xn[2] = (v.z - mu) * rs * gv.z + bv.z;
    xn[3] = (v.w - mu) * rs * gv.w + bv.w;
    short4 o;
    o.x = f2bf(xn[0]); o.y = f2bf(xn[1]); o.z = f2bf(xn[2]); o.w = f2bf(xn[3]);
    ((short4*)(xo + (long long)t * D_))[tid] = o;

    float a8[8] = {0, 0, 0, 0, 0, 0, 0, 0};
#pragma unroll
    for (int q = 0; q < 4; q++) {
        const int d = tid * 4 + q;
        const float4 w0 = ((const float4*)(wr + d * 8))[0];
        const float4 w1 = ((const float4*)(wr + d * 8))[1];
        a8[0] += xn[q] * w0.x; a8[1] += xn[q] * w0.y; a8[2] += xn[q] * w0.z; a8[3] += xn[q] * w0.w;
        a8[4] += xn[q] * w1.x; a8[5] += xn[q] * w1.y; a8[6] += xn[q] * w1.z; a8[7] += xn[q] * w1.w;
    }
    __shared__ float lred[32];
#pragma unroll
    for (int e = 0; e < 8; e++) {
        float vv = a8[e];
#pragma unroll
        for (int off = 32; off; off >>= 1) vv += __shfl_xor(vv, off, 64);
        if ((tid & 63) == 0) lred[(tid >> 6) * 8 + e] = vv;
    }
    __syncthreads();
    if (tid == 0) {
        float lg[8];
#pragma unroll
        for (int e = 0; e < 8; e++) lg[e] = lred[e] + lred[8 + e] + lred[16 + e] + lred[24 + e];
        int e0 = 0;
        for (int e = 1; e < 8; e++) if (lg[e] > lg[e0]) e0 = e;
        int e1 = (e0 == 0) ? 1 : 0;
        for (int e = 0; e < 8; e++) if (e != e0 && lg[e] > lg[e1]) e1 = e;
        const float mx = lg[e0];
        float den = 0.f;
        for (int e = 0; e < 8; e++) den += expf(lg[e] - mx);
        const float p0 = expf(lg[e0] - mx) / den;
        const float p1 = expf(lg[e1] - mx) / den;
        const float inv = 1.0f / (p0 + p1);
        topi[t * 2] = e0; topi[t * 2 + 1] = e1;
        gates[t * 2] = p0 * inv; gates[t * 2 + 1] = p1 * inv;
    }
}

// ---------------- slot-major capacity scan ----------------
__global__ __launch_bounds__(256) void route_scan(const int* __restrict__ topi,
    const float* __restrict__ gates, int* __restrict__ posc, float* __restrict__ wv)
{
    const int tid = threadIdx.x;
    const int w = tid >> 6, lane = tid & 63;
    __shared__ int wsum[4 * 8];
    int cnt[8] = {0, 0, 0, 0, 0, 0, 0, 0};
    const int base_r = tid * 64;
    for (int i = 0; i < 64; i++) {
        const int r = base_r + i;
        const int k = r >> 13, t = r & (T_ - 1);
        cnt[topi[t * 2 + k]]++;
    }
    int excl[8];
#pragma unroll
    for (int e = 0; e < 8; e++) {
        int x = cnt[e];
#pragma unroll
        for (int off = 1; off < 64; off <<= 1) {
            int y = __shfl_up(x, off, 64);
            if (lane >= off) x += y;
        }
        excl[e] = x - cnt[e];
        if (lane == 63) wsum[w * 8 + e] = x;
    }
    __syncthreads();
    int pos[8];
#pragma unroll
    for (int e = 0; e < 8; e++) {
        int s = 0;
        for (int ww = 0; ww < 4; ww++) if (ww < w) s += wsum[ww * 8 + e];
        pos[e] = s + excl[e];
    }
    for (int i = 0; i < 64; i++) {
        const int r = base_r + i;
        const int k = r >> 13, t = r & (T_ - 1);
        const int e = topi[t * 2 + k];
        const int p = pos[e]++;
        const bool keep = p < CAP_;
        posc[r] = keep ? p : -1;
        wv[r] = keep ? gates[t * 2 + k] : 0.0f;
    }
}

// ---------------- dispatch copy ----------------
__global__ __launch_bounds__(128) void dispatch_kernel(const short* __restrict__ xn2,
    const int* __restrict__ topi, const int* __restrict__ posc, short* __restrict__ disp)
{
    const int r = blockIdx.x;
    const int p = posc[r];
    if (p < 0) return;
    const int k = r >> 13, t = r & (T_ - 1);
    const int e = topi[t * 2 + k];
    const int tid = threadIdx.x;
    *(s8v*)&disp[((long long)e * CAP_ + p) * D_ + tid * 8] =
        *(const s8v*)&xn2[(long long)t * D_ + tid * 8];
}

// ---------------- combine ----------------
__global__ __launch_bounds__(256) void combine_kernel(const float* __restrict__ x1,
    const float* __restrict__ ys, const float* __restrict__ eo,
    const int* __restrict__ topi, const int* __restrict__ posc,
    const float* __restrict__ wv, float* __restrict__ out)
{
    const int t = blockIdx.x, tid = threadIdx.x;
    float4 a = *(const float4*)&x1[(long long)t * D_ + tid * 4];
    const float4 b = *(const float4*)&ys[(long long)t * D_ + tid * 4];
    a.x += b.x; a.y += b.y; a.z += b.z; a.w += b.w;
#pragma unroll
    for (int k = 0; k < 2; k++) {
        const int r = k * T_ + t;
        const int p = posc[r];
        if (p >= 0) {
            const int e = topi[t * 2 + k];
            const float wt = wv[r];
            const float4 c = *(const float4*)&eo[((long long)e * CAP_ + p) * D_ + tid * 4];
            a.x += wt * c.x; a.y += wt * c.y; a.z += wt * c.z; a.w += wt * c.w;
        }
    }
    *(float4*)&out[(long long)t * D_ + tid * 4] = a;
}

// ---------------- single-plane bf16 GEMM, z-batched (MoE + shared path) ----------------
// EPI: 1 = bias+gelu -> bf16 ; 2 = bias -> f32
// blockIdx.z selects a slab: A += z*sA, Bt += z*sB, bias += z*sBias, C += z*sC (elements).
template <int EPI>
__global__ __launch_bounds__(256) void gemm_btz(
    const short* __restrict__ A, const short* __restrict__ Bt,
    const float* __restrict__ bias, void* __restrict__ Cout,
    int M, int N, int K, int ldc,
    long long sA, long long sB, long long sBias, long long sC)
{
    __shared__ __align__(16) short lA[128 * 32];
    __shared__ __align__(16) short lB[128 * 32];
    const int z = blockIdx.z;
    A += (long long)z * sA;
    Bt += (long long)z * sB;
    bias += (long long)z * sBias;
    const int tid = threadIdx.x;
    const int wvi = tid >> 6, lane = tid & 63, lid = lane & 15, quad = lane >> 4;
    const int wm = wvi >> 1, wn = wvi & 1;
    const int mBase = blockIdx.y * 128, nBase = blockIdx.x * 128;
    f4v acc[4][4];
#pragma unroll
    for (int i = 0; i < 4; i++)
#pragma unroll
        for (int j = 0; j < 4; j++) acc[i][j] = f4zero();
    const long long aOff0 = (long long)(mBase + (tid >> 2)) * K + (tid & 3) * 8;
    const long long aOff1 = aOff0 + 64LL * K;
    const long long bOff0 = (long long)(nBase + (tid >> 2)) * K + (tid & 3) * 8;
    const long long bOff1 = bOff0 + 64LL * K;
    const int wofs = wvi << 9;
    for (int k0 = 0; k0 < K; k0 += 32) {
        __syncthreads();
        GLL(A + aOff0 + k0, &lA[wofs]);  GLL(A + aOff1 + k0, &lA[2048 + wofs]);
        GLL(Bt + bOff0 + k0, &lB[wofs]); GLL(Bt + bOff1 + k0, &lB[2048 + wofs]);
        __syncthreads();
        s8v af[4], bf[4];
#pragma unroll
        for (int i = 0; i < 4; i++)
            af[i] = *(const s8v*)&lA[(wm * 64 + i * 16 + lid) * 32 + quad * 8];
#pragma unroll
        for (int j = 0; j < 4; j++)
            bf[j] = *(const s8v*)&lB[(wn * 64 + j * 16 + lid) * 32 + quad * 8];
#pragma unroll
        for (int i = 0; i < 4; i++)
#pragma unroll
            for (int j = 0; j < 4; j++)
                acc[i][j] = __builtin_amdgcn_mfma_f32_16x16x32_bf16(af[i], bf[j], acc[i][j], 0, 0, 0);
    }
    const int mW = mBase + wm * 64 + quad * 4;
    const int nW = nBase + wn * 64 + lid;
    short* Cs = (short*)Cout + (long long)z * sC;
    float* Cf = (float*)Cout + (long long)z * sC;
#pragma unroll
    for (int j = 0; j < 4; j++) {
        const int n = nW + j * 16;
        const float bn = bias[n];
#pragma unroll
        for (int i = 0; i < 4; i++) {
            const int m = mW + i * 16;
#pragma unroll
            for (int r = 0; r < 4; r++) {
                float v = acc[i][j][r] + bn;
                if (EPI == 1) { v = gelu_f(v); Cs[(long long)(m + r) * ldc + n] = f2bf(v); }
                else          { Cf[(long long)(m + r) * ldc + n] = v; }
            }
        }
    }
}

// ---------------- split hi/lo GEMM: C = (Ah+Al) * (Bh+Bl)^T  (3-term) ----------------
// EPI: 0 = bias -> dual bf16 planes ; 1 = bias + resid -> f32
// Bias is selected per 1024-column segment (allows fused QKV: N=3072).
template <int EPI>
__global__ __launch_bounds__(256) void gemm_hl(
    const short* __restrict__ Ah, const short* __restrict__ Al,
    const short* __restrict__ Bh, const short* __restrict__ Bl,
    const float* __restrict__ biasQ, const float* __restrict__ biasK,
    const float* __restrict__ biasV, const float* __restrict__ resid,
    short* __restrict__ Ch, short* __restrict__ Cl, float* __restrict__ Cf,
    int M, int N, int K, int ldc)
{
    __shared__ __align__(16) short lAh[4096], lAl[4096], lBh[4096], lBl[4096];
    const int tid = threadIdx.x;
    const int wvi = tid >> 6, lane = tid & 63, lid = lane & 15, quad = lane >> 4;
    const int wm = wvi >> 1, wn = wvi & 1;
    const int mBase = blockIdx.y * 128, nBase = blockIdx.x * 128;
    f4v acc[4][4];
#pragma unroll
    for (int i = 0; i < 4; i++)
#pragma unroll
        for (int j = 0; j < 4; j++) acc[i][j] = f4zero();
    const long long aOff0 = (long long)(mBase + (tid >> 2)) * K + (tid & 3) * 8;
    const long long aOff1 = aOff0 + 64LL * K;
    const long long bOff0 = (long long)(nBase + (tid >> 2)) * K + (tid & 3) * 8;
    const long long bOff1 = bOff0 + 64LL * K;
    const int wofs = wvi << 9;
    for (int k0 = 0; k0 < K; k0 += 32) {
        __syncthreads();
        GLL(Ah + aOff0 + k0, &lAh[wofs]);  GLL(Ah + aOff1 + k0, &lAh[2048 + wofs]);
        GLL(Al + aOff0 + k0, &lAl[wofs]);  GLL(Al + aOff1 + k0, &lAl[2048 + wofs]);
        GLL(Bh + bOff0 + k0, &lBh[wofs]);  GLL(Bh + bOff1 + k0, &lBh[2048 + wofs]);
        GLL(Bl + bOff0 + k0, &lBl[wofs]);  GLL(Bl + bOff1 + k0, &lBl[2048 + wofs]);
        __syncthreads();
        s8v ah[4], al[4], bh[4], bl[4];
#pragma unroll
        for (int i = 0; i < 4; i++) {
            const int ro = (wm * 64 + i * 16 + lid) * 32 + quad * 8;
            ah[i] = *(const s8v*)&lAh[ro];
            al[i] = *(const s8v*)&lAl[ro];
        }
#pragma unroll
        for (int j = 0; j < 4; j++) {
            const int ro = (wn * 64 + j * 16 + lid) * 32 + quad * 8;
            bh[j] = *(const s8v*)&lBh[ro];
            bl[j] = *(const s8v*)&lBl[ro];
        }
#pragma unroll
        for (int i = 0; i < 4; i++)
#pragma unroll
            for (int j = 0; j < 4; j++) {
                acc[i][j] = __builtin_amdgcn_mfma_f32_16x16x32_bf16(ah[i], bh[j], acc[i][j], 0, 0, 0);
                acc[i][j] = __builtin_amdgcn_mfma_f32_16x16x32_bf16(ah[i], bl[j], acc[i][j], 0, 0, 0);
                acc[i][j] = __builtin_amdgcn_mfma_f32_16x16x32_bf16(al[i], bh[j], acc[i][j], 0, 0, 0);
            }
    }
    const int mW = mBase + wm * 64 + quad * 4;
    const int nW = nBase + wn * 64 + lid;
#pragma unroll
    for (int j = 0; j < 4; j++) {
        const int n = nW + j * 16;
        const float* bp = (n < 1024) ? biasQ : ((n < 2048) ? biasK : biasV);
        const float bn = bp[n & 1023];
#pragma unroll
        for (int i = 0; i < 4; i++) {
            const int m = mW + i * 16;
#pragma unroll
            for (int r = 0; r < 4; r++) {
                const float v = acc[i][j][r] + bn;
                const long long o = (long long)(m + r) * ldc + n;
                if (EPI == 0) {
                    const short h = f2bf(v);
                    Ch[o] = h;
                    Cl[o] = f2bf(v - b2f(h));
                } else {
                    Cf[o] = v + resid[o];
                }
            }
        }
    }
}

// ---------------- flash attention, split hi/lo ----------------
// V-transpose LDS tile uses an XOR swizzle keyed on (row>>3)&3 to kill the
// 16-way bank conflict of the column-scatter store (R1: conflicts 1.55e8 -> 5.45e7).
__global__ __launch_bounds__(256) void flash_attn_hl(const short* __restrict__ qkvh,
    const short* __restrict__ qkvl, const unsigned char* __restrict__ mask,
    short* __restrict__ attnh, short* __restrict__ attnl)
{
    __shared__ __align__(16) short lKh[32 * 72], lKl[32 * 72];
    __shared__ __align__(16) short lVth[64 * 40], lVtl[64 * 40];
    __shared__ __align__(16) short lPh[4 * 16 * 40], lPl[4 * 16 * 40];
    const int tid = threadIdx.x;
    const int w = tid >> 6, lane = tid & 63, lid = lane & 15, quad = lane >> 4;
    const int bh = blockIdx.y;
    const int b = bh >> 4, h = bh & 15;
    const int q0row = blockIdx.x * 64 + w * 16;

    const long long rowQ = (long long)(b * S_ + q0row + lid) * 3072 + h * 64;
    const s8v qh0 = *(const s8v*)&qkvh[rowQ + quad * 8];
    const s8v qh1 = *(const s8v*)&qkvh[rowQ + 32 + quad * 8];
    const s8v ql0 = *(const s8v*)&qkvl[rowQ + quad * 8];
    const s8v ql1 = *(const s8v*)&qkvl[rowQ + 32 + quad * 8];

    float m_run[4], l_run[4];
    f4v o[4];
#pragma unroll
    for (int r = 0; r < 4; r++) { m_run[r] = -1e30f; l_run[r] = 0.0f; }
#pragma unroll
    for (int dt = 0; dt < 4; dt++) o[dt] = f4zero();

    const unsigned char* mrow = mask + b * S_;
    const int srow = tid >> 3, sgrp = tid & 7;

    for (int c0 = 0; c0 < S_; c0 += 32) {
        __syncthreads();
        {
            const long long gk = (long long)(b * S_ + c0 + srow) * 3072 + 1024 + h * 64 + sgrp * 8;
            *(s8v*)&lKh[srow * 72 + sgrp * 8] = *(const s8v*)&qkvh[gk];
            *(s8v*)&lKl[srow * 72 + sgrp * 8] = *(const s8v*)&qkvl[gk];
            const long long gv = (long long)(b * S_ + c0 + srow) * 3072 + 2048 + h * 64 + sgrp * 8;
            const s8v vh = *(const s8v*)&qkvh[gv];
            const s8v vl = *(const s8v*)&qkvl[gv];
            const int vcol = srow ^ ((sgrp & 3) << 3);   // XOR-swizzled k-column
#pragma unroll
            for (int jj = 0; jj < 8; jj++) {
                lVth[(sgrp * 8 + jj) * 40 + vcol] = vh[jj];
                lVtl[(sgrp * 8 + jj) * 40 + vcol] = vl[jj];
            }
        }
        __syncthreads();

        f4v s0 = f4zero(), s1 = f4zero();
        {
            const int r0 = lid * 72 + quad * 8;
            const s8v kh0a = *(const s8v*)&lKh[r0];
            const s8v kh0b = *(const s8v*)&lKh[r0 + 32];
            const s8v kl0a = *(const s8v*)&lKl[r0];
            const s8v kl0b = *(const s8v*)&lKl[r0 + 32];
            s0 = __builtin_amdgcn_mfma_f32_16x16x32_bf16(qh0, kh0a, s0, 0, 0, 0);
            s0 = __builtin_amdgcn_mfma_f32_16x16x32_bf16(qh1, kh0b, s0, 0, 0, 0);
            s0 = __builtin_amdgcn_mfma_f32_16x16x32_bf16(qh0, kl0a, s0, 0, 0, 0);
            s0 = __builtin_amdgcn_mfma_f32_16x16x32_bf16(qh1, kl0b, s0, 0, 0, 0);
            s0 = __builtin_amdgcn_mfma_f32_16x16x32_bf16(ql0, kh0a, s0, 0, 0, 0);
            s0 = __builtin_amdgcn_mfma_f32_16x16x32_bf16(ql1, kh0b, s0, 0, 0, 0);
            const int r1i = (16 + lid) * 72 + quad * 8;
            const s8v kh1a = *(const s8v*)&lKh[r1i];
            const s8v kh1b = *(const s8v*)&lKh[r1i + 32];
            const s8v kl1a = *(const s8v*)&lKl[r1i];
            const s8v kl1b = *(const s8v*)&lKl[r1i + 32];
            s1 = __builtin_amdgcn_mfma_f32_16x16x32_bf16(qh0, kh1a, s1, 0, 0, 0);
            s1 = __builtin_amdgcn_mfma_f32_16x16x32_bf16(qh1, kh1b, s1, 0, 0, 0);
            s1 = __builtin_amdgcn_mfma_f32_16x16x32_bf16(qh0, kl1a, s1, 0, 0, 0);
            s1 = __builtin_amdgcn_mfma_f32_16x16x32_bf16(qh1, kl1b, s1, 0, 0, 0);
            s1 = __builtin_amdgcn_mfma_f32_16x16x32_bf16(ql0, kh1a, s1, 0, 0, 0);
            s1 = __builtin_amdgcn_mfma_f32_16x16x32_bf16(ql1, kh1b, s1, 0, 0, 0);
        }
        const bool mk0 = mrow[c0 + lid] != 0;
        const bool mk1 = mrow[c0 + 16 + lid] != 0;
        float p0[4], p1[4];
#pragma unroll
        for (int r = 0; r < 4; r++) {
            p0[r] = mk0 ? -1e30f : s0[r] * 0.125f;
            p1[r] = mk1 ? -1e30f : s1[r] * 0.125f;
        }
        float mc[4];
#pragma unroll
        for (int r = 0; r < 4; r++) mc[r] = fmaxf(p0[r], p1[r]);
#pragma unroll
        for (int off = 1; off < 16; off <<= 1)
#pragma unroll
            for (int r = 0; r < 4; r++) mc[r] = fmaxf(mc[r], __shfl_xor(mc[r], off, 64));
        float alpha[4], rsum[4];
#pragma unroll
        for (int r = 0; r < 4; r++) {
            const float mn = fmaxf(m_run[r], mc[r]);
            alpha[r] = __expf(m_run[r] - mn);
            m_run[r] = mn;
            p0[r] = __expf(p0[r] - mn);
            p1[r] = __expf(p1[r] - mn);
            rsum[r] = p0[r] + p1[r];
        }
#pragma unroll
        for (int off = 1; off < 16; off <<= 1)
#pragma unroll
            for (int r = 0; r < 4; r++) rsum[r] += __shfl_xor(rsum[r], off, 64);
#pragma unroll
        for (int r = 0; r < 4; r++) l_run[r] = l_run[r] * alpha[r] + rsum[r];
#pragma unroll
        for (int dt = 0; dt < 4; dt++)
#pragma unroll
            for (int r = 0; r < 4; r++) o[dt][r] *= alpha[r];
#pragma unroll
        for (int r = 0; r < 4; r++) {
            const int o0 = w * 640 + (quad * 4 + r) * 40 + lid;
            const short h0 = f2bf(p0[r]);
            const short h1 = f2bf(p1[r]);
            lPh[o0] = h0;      lPl[o0] = f2bf(p0[r] - b2f(h0));
            lPh[o0 + 16] = h1; lPl[o0 + 16] = f2bf(p1[r] - b2f(h1));
        }
        __syncthreads();
        const s8v pah = *(const s8v*)&lPh[w * 640 + lid * 40 + quad * 8];
        const s8v pal = *(const s8v*)&lPl[w * 640 + lid * 40 + quad * 8];
#pragma unroll
        for (int dt = 0; dt < 4; dt++) {
            const int d = dt * 16 + lid;
            const int x3 = (dt * 2 + (lid >> 3)) & 3;          // (d>>3) & 3
            const int ro = d * 40 + ((quad ^ x3) << 3);        // de-swizzled b128 read
            const s8v bvh = *(const s8v*)&lVth[ro];
            const s8v bvl = *(const s8v*)&lVtl[ro];
            o[dt] = __builtin_amdgcn_mfma_f32_16x16x32_bf16(pah, bvh, o[dt], 0, 0, 0);
            o[dt] = __builtin_amdgcn_mfma_f32_16x16x32_bf16(pah, bvl, o[dt], 0, 0, 0);
            o[dt] = __builtin_amdgcn_mfma_f32_16x16x32_bf16(pal, bvh, o[dt], 0, 0, 0);
        }
    }
#pragma unroll
    for (int dt = 0; dt < 4; dt++)
#pragma unroll
        for (int r = 0; r < 4; r++) {
            const int m = q0row + quad * 4 + r;
            const float v = o[dt][r] / l_run[r];
            const long long idx = (long long)(b * S_ + m) * D_ + h * 64 + dt * 16 + lid;
            const short hh = f2bf(v);
            attnh[idx] = hh;
            attnl[idx] = f2bf(v - b2f(hh));
        }
}

// ---------------- workspace layout (bytes) ----------------
constexpr long long SZ_DD2   = (long long)D_ * D_ * 2;
constexpr long long OFF_WQKVH = 0;
constexpr long long OFF_WQKVL = OFF_WQKVH + 3 * SZ_DD2;
constexpr long long OFF_WOH   = OFF_WQKVL + 3 * SZ_DD2;
constexpr long long OFF_WOL   = OFF_WOH + SZ_DD2;
constexpr long long OFF_W1T   = OFF_WOL + SZ_DD2;
constexpr long long OFF_W2T   = OFF_W1T + (long long)E_ * F_ * D_ * 2;
constexpr long long OFF_WS1T  = OFF_W2T + (long long)E_ * D_ * F_ * 2;
constexpr long long OFF_WS2T  = OFF_WS1T + (long long)FS_ * D_ * 2;
constexpr long long OFF_X1    = OFF_WS2T + (long long)D_ * FS_ * 2;
constexpr long long OFF_XN2   = OFF_X1 + (long long)T_ * D_ * 4;
constexpr long long OFF_TOPI  = OFF_XN2 + (long long)T_ * D_ * 2;
constexpr long long OFF_GATES = OFF_TOPI + (long long)T_ * 2 * 4;
constexpr long long OFF_POSC  = OFF_GATES + (long long)T_ * 2 * 4;
constexpr long long OFF_WVAL  = OFF_POSC + (long long)2 * T_ * 4;
constexpr long long ZONE      = OFF_WVAL + (long long)2 * T_ * 4;
// attention phase
constexpr long long OFF_XH1   = ZONE;
constexpr long long OFF_XL1   = OFF_XH1 + (long long)T_ * D_ * 2;
constexpr long long OFF_QKVH  = OFF_XL1 + (long long)T_ * D_ * 2;
constexpr long long OFF_QKVL  = OFF_QKVH + (long long)T_ * 3 * D_ * 2;
constexpr long long OFF_ATTNH = OFF_QKVL + (long long)T_ * 3 * D_ * 2;
constexpr long long OFF_ATTNL = OFF_ATTNH + (long long)T_ * D_ * 2;
// MoE phase (reuses attention zone)
constexpr long long OFF_DISP  = ZONE;
constexpr long long OFF_H     = OFF_DISP + (long long)E_ * CAP_ * D_ * 2;   // 4-expert H slab
constexpr long long OFF_EO    = OFF_H + (long long)4 * CAP_ * F_ * 2;
constexpr long long OFF_YS    = OFF_EO + (long long)E_ * CAP_ * D_ * 4;
constexpr long long OFF_HS    = ZONE;  // after experts (disp dead)

extern "C" void kernel_launch(void* const* d_in, const int* in_sizes, int n_in,
                              void* d_out, int out_size, void* d_ws, size_t ws_size,
                              hipStream_t stream)
{
    (void)in_sizes; (void)n_in; (void)out_size; (void)ws_size;
    const float* x       = (const float*)d_in[0];
    const unsigned char* mask = (const unsigned char*)d_in[1];
    const float* ln1g    = (const float*)d_in[2];
    const float* ln1b    = (const float*)d_in[3];
    const float* wq      = (const float*)d_in[4];
    const float* bq      = (const float*)d_in[5];
    const float* wk      = (const float*)d_in[6];
    const float* bk      = (const float*)d_in[7];
    const float* wvp     = (const float*)d_in[8];
    const float* bvv     = (const float*)d_in[9];
    const float* wo      = (const float*)d_in[10];
    const float* bo      = (const float*)d_in[11];
    const float* ln2g    = (const float*)d_in[12];
    const float* ln2b    = (const float*)d_in[13];
    const float* wrouter = (const float*)d_in[14];
    const float* w1      = (const float*)d_in[15];
    const float* b1      = (const float*)d_in[16];
    const float* w2      = (const float*)d_in[17];
    const float* b2      = (const float*)d_in[18];
    const float* ws1     = (const float*)d_in[19];
    const float* bs1     = (const float*)d_in[20];
    const float* ws2     = (const float*)d_in[21];
    const float* bs2     = (const float*)d_in[22];
    float* out = (float*)d_out;
    char* ws = (char*)d_ws;

    short* wqkvh = (short*)(ws + OFF_WQKVH);
    short* wqkvl = (short*)(ws + OFF_WQKVL);
    short* woh   = (short*)(ws + OFF_WOH);
    short* wol   = (short*)(ws + OFF_WOL);
    short* w1T   = (short*)(ws + OFF_W1T);
    short* w2T   = (short*)(ws + OFF_W2T);
    short* ws1T  = (short*)(ws + OFF_WS1T);
    short* ws2T  = (short*)(ws + OFF_WS2T);
    float* x1    = (float*)(ws + OFF_X1);
    short* xn2   = (short*)(ws + OFF_XN2);
    int*   topi  = (int*)(ws + OFF_TOPI);
    float* gates = (float*)(ws + OFF_GATES);
    int*   posc  = (int*)(ws + OFF_POSC);
    float* wval  = (float*)(ws + OFF_WVAL);
    short* xh1   = (short*)(ws + OFF_XH1);
    short* xl1   = (short*)(ws + OFF_XL1);
    short* qkvh  = (short*)(ws + OFF_QKVH);
    short* qkvl  = (short*)(ws + OFF_QKVL);
    short* attnh = (short*)(ws + OFF_ATTNH);
    short* attnl = (short*)(ws + OFF_ATTNL);
    short* disp  = (short*)(ws + OFF_DISP);
    short* hbuf  = (short*)(ws + OFF_H);
    float* eo    = (float*)(ws + OFF_EO);
    short* hs    = (short*)(ws + OFF_HS);
    float* ysb   = (float*)(ws + OFF_YS);

    const dim3 tb(256);
    transcvt2<<<dim3(32, 32), tb, 0, stream>>>(wq,  wqkvh,               wqkvl,               1024, 1024);
    transcvt2<<<dim3(32, 32), tb, 0, stream>>>(wk,  wqkvh + 1024 * 1024, wqkvl + 1024 * 1024, 1024, 1024);
    transcvt2<<<dim3(32, 32), tb, 0, stream>>>(wvp, wqkvh + 2 * 1024 * 1024, wqkvl + 2 * 1024 * 1024, 1024, 1024);
    transcvt2<<<dim3(32, 32), tb, 0, stream>>>(wo,  woh, wol, 1024, 1024);
    transcvt<<<dim3(128, 32, 8), tb, 0, stream>>>(w1, w1T, 1024, 4096);
    transcvt<<<dim3(32, 128, 8), tb, 0, stream>>>(w2, w2T, 4096, 1024);
    transcvt<<<dim3(64, 32, 1), tb, 0, stream>>>(ws1, ws1T, 1024, 2048);
    transcvt<<<dim3(32, 64, 1), tb, 0, stream>>>(ws2, ws2T, 2048, 1024);

    ln1_split<<<T_, 256, 0, stream>>>(x, ln1g, ln1b, xh1, xl1);

    // fused QKV: B = [3072,1024] (wq^T|wk^T|wv^T contiguous), per-segment bias
    gemm_hl<0><<<dim3(24, 64), 256, 0, stream>>>(xh1, xl1, wqkvh, wqkvl,
        bq, bk, bvv, nullptr, qkvh, qkvl, nullptr, T_, 3072, 1024, 3072);

    flash_attn_hl<<<dim3(32, 64), 256, 0, stream>>>(qkvh, qkvl, mask, attnh, attnl);

    gemm_hl<1><<<dim3(8, 64), 256, 0, stream>>>(attnh, attnl, woh, wol,
        bo, bo, bo, x, nullptr, nullptr, x1, T_, 1024, 1024, 1024);

    ln2_router_kernel<<<T_, 256, 0, stream>>>(x1, ln2g, ln2b, wrouter, xn2, topi, gates);
    route_scan<<<1, 256, 0, stream>>>(topi, gates, posc, wval);
    dispatch_kernel<<<2 * T_, 128, 0, stream>>>(xn2, topi, posc, disp);

    // experts batched over blockIdx.z in 2 groups of 4 (H slab = 4 experts)
    for (int g = 0; g < 2; g++) {
        const long long e0 = (long long)g * 4;
        gemm_btz<1><<<dim3(32, 20, 4), 256, 0, stream>>>(
            disp + e0 * CAP_ * D_, w1T + e0 * F_ * D_, b1 + e0 * F_, hbuf,
            CAP_, F_, 1024, F_,
            (long long)CAP_ * D_, (long long)F_ * D_, (long long)F_, (long long)CAP_ * F_);
        gemm_btz<2><<<dim3(8, 20, 4), 256, 0, stream>>>(
            hbuf, w2T + e0 * D_ * F_, b2 + e0 * D_, eo + e0 * CAP_ * D_,
            CAP_, 1024, F_, 1024,
            (long long)CAP_ * F_, (long long)D_ * F_, (long long)D_, (long long)CAP_ * D_);
    }

    gemm_btz<1><<<dim3(16, 64, 1), 256, 0, stream>>>(xn2, ws1T, bs1, hs,
        T_, FS_, 1024, FS_, 0, 0, 0, 0);
    gemm_btz<2><<<dim3(8, 64, 1), 256, 0, stream>>>(hs, ws2T, bs2, ysb,
        T_, 1024, FS_, 1024, 0, 0, 0, 0);

    combine_kernel<<<T_, 256, 0, stream>>>(x1, ysb, eo, topi, posc, wval, out);
}

// Round 3
// 1928.284 us; speedup vs baseline: 1.4533x; 1.0479x over previous
//
#include <hip/hip_runtime.h>
#include <hip/hip_bf16.h>
#include <stdint.h>

#define D_ 1024
#define S_ 2048
#define B_ 4
#define H_ 16
#define T_ 8192
#define E_ 8
#define CAP_ 2560
#define F_ 4096
#define FS_ 2048

typedef __attribute__((ext_vector_type(8))) short s8v;
typedef __attribute__((ext_vector_type(4))) float f4v;

#define GLL(gp, lp) __builtin_amdgcn_global_load_lds( \
    (const __attribute__((address_space(1))) unsigned int*)(gp), \
    (__attribute__((address_space(3))) unsigned int*)(lp), 16, 0, 0)

__device__ inline short f2bf(float f) {
    union { float f; unsigned u; } v; v.f = f;
    unsigned r = (v.u + 0x7fffu + ((v.u >> 16) & 1u)) >> 16;
    return (short)(r & 0xffffu);
}
__device__ inline float b2f(short h) {
    union { unsigned u; float f; } v; v.u = ((unsigned)(unsigned short)h) << 16; return v.f;
}
__device__ inline float gelu_f(float x) {
    return 0.5f * x * (1.0f + erff(x * 0.7071067811865475f));
}
__device__ inline f4v f4zero() { f4v z; z[0]=0.f; z[1]=0.f; z[2]=0.f; z[3]=0.f; return z; }

// pack (a,b) -> hi-plane bf16 pair; lo-plane residual pair written to *lo
__device__ inline unsigned pk2(float a, float b, unsigned* lo) {
    const short ha = f2bf(a), hb = f2bf(b);
    const short la = f2bf(a - b2f(ha)), lb = f2bf(b - b2f(hb));
    *lo = ((unsigned)(unsigned short)lb << 16) | (unsigned)(unsigned short)la;
    return ((unsigned)(unsigned short)hb << 16) | (unsigned)(unsigned short)ha;
}

// ---------------- transpose + fp32->bf16 (single plane, MoE weights) ----------------
__global__ __launch_bounds__(256) void transcvt(const float* __restrict__ in,
                                                short* __restrict__ out, int R, int C)
{
    __shared__ float tile[32][33];
    const int tid = threadIdx.x;
    const int tx = tid & 31, ty = tid >> 5;
    const long long ib = (long long)blockIdx.z * R * C;
    const int r0 = blockIdx.y * 32, c0 = blockIdx.x * 32;
#pragma unroll
    for (int i = 0; i < 4; i++)
        tile[ty + i * 8][tx] = in[ib + (long long)(r0 + ty + i * 8) * C + c0 + tx];
    __syncthreads();
#pragma unroll
    for (int i = 0; i < 4; i++)
        out[ib + (long long)(c0 + ty + i * 8) * R + r0 + tx] = f2bf(tile[tx][ty + i * 8]);
}

// ---------------- transpose + hi/lo split (attention weights) ----------------
__global__ __launch_bounds__(256) void transcvt2(const float* __restrict__ in,
    short* __restrict__ oh, short* __restrict__ ol, int R, int C)
{
    __shared__ float tile[32][33];
    const int tid = threadIdx.x;
    const int tx = tid & 31, ty = tid >> 5;
    const int r0 = blockIdx.y * 32, c0 = blockIdx.x * 32;
#pragma unroll
    for (int i = 0; i < 4; i++)
        tile[ty + i * 8][tx] = in[(long long)(r0 + ty + i * 8) * C + c0 + tx];
    __syncthreads();
#pragma unroll
    for (int i = 0; i < 4; i++) {
        const float v = tile[tx][ty + i * 8];
        const short h = f2bf(v);
        const long long o = (long long)(c0 + ty + i * 8) * R + r0 + tx;
        oh[o] = h;
        ol[o] = f2bf(v - b2f(h));
    }
}

// ---------------- LN1: fp32 x -> hi/lo bf16 planes ----------------
__global__ __launch_bounds__(256) void ln1_split(const float* __restrict__ x,
    const float* __restrict__ g, const float* __restrict__ bta,
    short* __restrict__ xh, short* __restrict__ xl)
{
    const int t = blockIdx.x, tid = threadIdx.x;
    const float4 v = ((const float4*)(x + (long long)t * D_))[tid];
    float s1 = v.x + v.y + v.z + v.w;
    float s2 = v.x * v.x + v.y * v.y + v.z * v.z + v.w * v.w;
#pragma unroll
    for (int off = 32; off; off >>= 1) { s1 += __shfl_xor(s1, off, 64); s2 += __shfl_xor(s2, off, 64); }
    __shared__ float r1[4], r2[4];
    if ((tid & 63) == 0) { r1[tid >> 6] = s1; r2[tid >> 6] = s2; }
    __syncthreads();
    s1 = r1[0] + r1[1] + r1[2] + r1[3];
    s2 = r2[0] + r2[1] + r2[2] + r2[3];
    const float mu = s1 * (1.0f / D_);
    const float var = s2 * (1.0f / D_) - mu * mu;
    const float rs = rsqrtf(var + 1e-5f);
    const float4 gv = ((const float4*)g)[tid];
    const float4 bv = ((const float4*)bta)[tid];
    float xn[4];
    xn[0] = (v.x - mu) * rs * gv.x + bv.x;
    xn[1] = (v.y - mu) * rs * gv.y + bv.y;
    xn[2] = (v.z - mu) * rs * gv.z + bv.z;
    xn[3] = (v.w - mu) * rs * gv.w + bv.w;
    short4 hh, ll;
    hh.x = f2bf(xn[0]); ll.x = f2bf(xn[0] - b2f(hh.x));
    hh.y = f2bf(xn[1]); ll.y = f2bf(xn[1] - b2f(hh.y));
    hh.z = f2bf(xn[2]); ll.z = f2bf(xn[2] - b2f(hh.z));
    hh.w = f2bf(xn[3]); ll.w = f2bf(xn[3] - b2f(hh.w));
    ((short4*)(xh + (long long)t * D_))[tid] = hh;
    ((short4*)(xl + (long long)t * D_))[tid] = ll;
}

// ---------------- LN2 + router (fp32 logits, bf16 xn out) ----------------
__global__ __launch_bounds__(256) void ln2_router_kernel(const float* __restrict__ x,
    const float* __restrict__ g, const float* __restrict__ bta, const float* __restrict__ wr,
    short* __restrict__ xo, int* __restrict__ topi, float* __restrict__ gates)
{
    const int t = blockIdx.x, tid = threadIdx.x;
    const float4 v = ((const float4*)(x + (long long)t * D_))[tid];
    float s1 = v.x + v.y + v.z + v.w;
    float s2 = v.x * v.x + v.y * v.y + v.z * v.z + v.w * v.w;
#pragma unroll
    for (int off = 32; off; off >>= 1) { s1 += __shfl_xor(s1, off, 64); s2 += __shfl_xor(s2, off, 64); }
    __shared__ float r1[4], r2[4];
    if ((tid & 63) == 0) { r1[tid >> 6] = s1; r2[tid >> 6] = s2; }
    __syncthreads();
    s1 = r1[0] + r1[1] + r1[2] + r1[3];
    s2 = r2[0] + r2[1] + r2[2] + r2[3];
    const float mu = s1 * (1.0f / D_);
    const float var = s2 * (1.0f / D_) - mu * mu;
    const float rs = rsqrtf(var + 1e-5f);
    const float4 gv = ((const float4*)g)[tid];
    const float4 bv = ((const float4*)bta)[tid];
    float xn[4];
    xn[0] = (v.x - mu) * rs * gv.x + bv.x;
    xn[1] = (v.y - mu) * rs * gv.y + bv.y;
    xn[2] = (v.z - mu) * rs * gv.z + bv.z;
    xn[3] = (v.w - mu) * rs * gv.w + bv.w;
    short4 o;
    o.x = f2bf(xn[0]); o.y = f2bf(xn[1]); o.z = f2bf(xn[2]); o.w = f2bf(xn[3]);
    ((short4*)(xo + (long long)t * D_))[tid] = o;

    float a8[8] = {0, 0, 0, 0, 0, 0, 0, 0};
#pragma unroll
    for (int q = 0; q < 4; q++) {
        const int d = tid * 4 + q;
        const float4 w0 = ((const float4*)(wr + d * 8))[0];
        const float4 w1 = ((const float4*)(wr + d * 8))[1];
        a8[0] += xn[q] * w0.x; a8[1] += xn[q] * w0.y; a8[2] += xn[q] * w0.z; a8[3] += xn[q] * w0.w;
        a8[4] += xn[q] * w1.x; a8[5] += xn[q] * w1.y; a8[6] += xn[q] * w1.z; a8[7] += xn[q] * w1.w;
    }
    __shared__ float lred[32];
#pragma unroll
    for (int e = 0; e < 8; e++) {
        float vv = a8[e];
#pragma unroll
        for (int off = 32; off; off >>= 1) vv += __shfl_xor(vv, off, 64);
        if ((tid & 63) == 0) lred[(tid >> 6) * 8 + e] = vv;
    }
    __syncthreads();
    if (tid == 0) {
        float lg[8];
#pragma unroll
        for (int e = 0; e < 8; e++) lg[e] = lred[e] + lred[8 + e] + lred[16 + e] + lred[24 + e];
        int e0 = 0;
        for (int e = 1; e < 8; e++) if (lg[e] > lg[e0]) e0 = e;
        int e1 = (e0 == 0) ? 1 : 0;
        for (int e = 0; e < 8; e++) if (e != e0 && lg[e] > lg[e1]) e1 = e;
        const float mx = lg[e0];
        float den = 0.f;
        for (int e = 0; e < 8; e++) den += expf(lg[e] - mx);
        const float p0 = expf(lg[e0] - mx) / den;
        const float p1 = expf(lg[e1] - mx) / den;
        const float inv = 1.0f / (p0 + p1);
        topi[t * 2] = e0; topi[t * 2 + 1] = e1;
        gates[t * 2] = p0 * inv; gates[t * 2 + 1] = p1 * inv;
    }
}

// ---------------- slot-major capacity scan ----------------
__global__ __launch_bounds__(256) void route_scan(const int* __restrict__ topi,
    const float* __restrict__ gates, int* __restrict__ posc, float* __restrict__ wv)
{
    const int tid = threadIdx.x;
    const int w = tid >> 6, lane = tid & 63;
    __shared__ int wsum[4 * 8];
    int cnt[8] = {0, 0, 0, 0, 0, 0, 0, 0};
    const int base_r = tid * 64;
    for (int i = 0; i < 64; i++) {
        const int r = base_r + i;
        const int k = r >> 13, t = r & (T_ - 1);
        cnt[topi[t * 2 + k]]++;
    }
    int excl[8];
#pragma unroll
    for (int e = 0; e < 8; e++) {
        int x = cnt[e];
#pragma unroll
        for (int off = 1; off < 64; off <<= 1) {
            int y = __shfl_up(x, off, 64);
            if (lane >= off) x += y;
        }
        excl[e] = x - cnt[e];
        if (lane == 63) wsum[w * 8 + e] = x;
    }
    __syncthreads();
    int pos[8];
#pragma unroll
    for (int e = 0; e < 8; e++) {
        int s = 0;
        for (int ww = 0; ww < 4; ww++) if (ww < w) s += wsum[ww * 8 + e];
        pos[e] = s + excl[e];
    }
    for (int i = 0; i < 64; i++) {
        const int r = base_r + i;
        const int k = r >> 13, t = r & (T_ - 1);
        const int e = topi[t * 2 + k];
        const int p = pos[e]++;
        const bool keep = p < CAP_;
        posc[r] = keep ? p : -1;
        wv[r] = keep ? gates[t * 2 + k] : 0.0f;
    }
}

// ---------------- dispatch copy ----------------
__global__ __launch_bounds__(128) void dispatch_kernel(const short* __restrict__ xn2,
    const int* __restrict__ topi, const int* __restrict__ posc, short* __restrict__ disp)
{
    const int r = blockIdx.x;
    const int p = posc[r];
    if (p < 0) return;
    const int k = r >> 13, t = r & (T_ - 1);
    const int e = topi[t * 2 + k];
    const int tid = threadIdx.x;
    *(s8v*)&disp[((long long)e * CAP_ + p) * D_ + tid * 8] =
        *(const s8v*)&xn2[(long long)t * D_ + tid * 8];
}

// ---------------- combine ----------------
__global__ __launch_bounds__(256) void combine_kernel(const float* __restrict__ x1,
    const float* __restrict__ ys, const float* __restrict__ eo,
    const int* __restrict__ topi, const int* __restrict__ posc,
    const float* __restrict__ wv, float* __restrict__ out)
{
    const int t = blockIdx.x, tid = threadIdx.x;
    float4 a = *(const float4*)&x1[(long long)t * D_ + tid * 4];
    const float4 b = *(const float4*)&ys[(long long)t * D_ + tid * 4];
    a.x += b.x; a.y += b.y; a.z += b.z; a.w += b.w;
#pragma unroll
    for (int k = 0; k < 2; k++) {
        const int r = k * T_ + t;
        const int p = posc[r];
        if (p >= 0) {
            const int e = topi[t * 2 + k];
            const float wt = wv[r];
            const float4 c = *(const float4*)&eo[((long long)e * CAP_ + p) * D_ + tid * 4];
            a.x += wt * c.x; a.y += wt * c.y; a.z += wt * c.z; a.w += wt * c.w;
        }
    }
    *(float4*)&out[(long long)t * D_ + tid * 4] = a;
}

// ---------------- single-plane bf16 GEMM, z-batched (MoE + shared path) ----------------
// EPI: 1 = bias+gelu -> bf16 ; 2 = bias -> f32
template <int EPI>
__global__ __launch_bounds__(256) void gemm_btz(
    const short* __restrict__ A, const short* __restrict__ Bt,
    const float* __restrict__ bias, void* __restrict__ Cout,
    int M, int N, int K, int ldc,
    long long sA, long long sB, long long sBias, long long sC)
{
    __shared__ __align__(16) short lA[128 * 32];
    __shared__ __align__(16) short lB[128 * 32];
    const int z = blockIdx.z;
    A += (long long)z * sA;
    Bt += (long long)z * sB;
    bias += (long long)z * sBias;
    const int tid = threadIdx.x;
    const int wvi = tid >> 6, lane = tid & 63, lid = lane & 15, quad = lane >> 4;
    const int wm = wvi >> 1, wn = wvi & 1;
    const int mBase = blockIdx.y * 128, nBase = blockIdx.x * 128;
    f4v acc[4][4];
#pragma unroll
    for (int i = 0; i < 4; i++)
#pragma unroll
        for (int j = 0; j < 4; j++) acc[i][j] = f4zero();
    const long long aOff0 = (long long)(mBase + (tid >> 2)) * K + (tid & 3) * 8;
    const long long aOff1 = aOff0 + 64LL * K;
    const long long bOff0 = (long long)(nBase + (tid >> 2)) * K + (tid & 3) * 8;
    const long long bOff1 = bOff0 + 64LL * K;
    const int wofs = wvi << 9;
    for (int k0 = 0; k0 < K; k0 += 32) {
        __syncthreads();
        GLL(A + aOff0 + k0, &lA[wofs]);  GLL(A + aOff1 + k0, &lA[2048 + wofs]);
        GLL(Bt + bOff0 + k0, &lB[wofs]); GLL(Bt + bOff1 + k0, &lB[2048 + wofs]);
        __syncthreads();
        s8v af[4], bf[4];
#pragma unroll
        for (int i = 0; i < 4; i++)
            af[i] = *(const s8v*)&lA[(wm * 64 + i * 16 + lid) * 32 + quad * 8];
#pragma unroll
        for (int j = 0; j < 4; j++)
            bf[j] = *(const s8v*)&lB[(wn * 64 + j * 16 + lid) * 32 + quad * 8];
#pragma unroll
        for (int i = 0; i < 4; i++)
#pragma unroll
            for (int j = 0; j < 4; j++)
                acc[i][j] = __builtin_amdgcn_mfma_f32_16x16x32_bf16(af[i], bf[j], acc[i][j], 0, 0, 0);
    }
    const int mW = mBase + wm * 64 + quad * 4;
    const int nW = nBase + wn * 64 + lid;
    short* Cs = (short*)Cout + (long long)z * sC;
    float* Cf = (float*)Cout + (long long)z * sC;
#pragma unroll
    for (int j = 0; j < 4; j++) {
        const int n = nW + j * 16;
        const float bn = bias[n];
#pragma unroll
        for (int i = 0; i < 4; i++) {
            const int m = mW + i * 16;
#pragma unroll
            for (int r = 0; r < 4; r++) {
                float v = acc[i][j][r] + bn;
                if (EPI == 1) { v = gelu_f(v); Cs[(long long)(m + r) * ldc + n] = f2bf(v); }
                else          { Cf[(long long)(m + r) * ldc + n] = v; }
            }
        }
    }
}

// ---------------- split hi/lo GEMM: C = (Ah+Al) * (Bh+Bl)^T  (3-term) ----------------
// EPI: 0 = bias -> dual bf16 planes ; 1 = bias + resid -> f32
// Bias is selected per 1024-column segment (allows fused QKV: N=3072).
template <int EPI>
__global__ __launch_bounds__(256) void gemm_hl(
    const short* __restrict__ Ah, const short* __restrict__ Al,
    const short* __restrict__ Bh, const short* __restrict__ Bl,
    const float* __restrict__ biasQ, const float* __restrict__ biasK,
    const float* __restrict__ biasV, const float* __restrict__ resid,
    short* __restrict__ Ch, short* __restrict__ Cl, float* __restrict__ Cf,
    int M, int N, int K, int ldc)
{
    __shared__ __align__(16) short lAh[4096], lAl[4096], lBh[4096], lBl[4096];
    const int tid = threadIdx.x;
    const int wvi = tid >> 6, lane = tid & 63, lid = lane & 15, quad = lane >> 4;
    const int wm = wvi >> 1, wn = wvi & 1;
    const int mBase = blockIdx.y * 128, nBase = blockIdx.x * 128;
    f4v acc[4][4];
#pragma unroll
    for (int i = 0; i < 4; i++)
#pragma unroll
        for (int j = 0; j < 4; j++) acc[i][j] = f4zero();
    const long long aOff0 = (long long)(mBase + (tid >> 2)) * K + (tid & 3) * 8;
    const long long aOff1 = aOff0 + 64LL * K;
    const long long bOff0 = (long long)(nBase + (tid >> 2)) * K + (tid & 3) * 8;
    const long long bOff1 = bOff0 + 64LL * K;
    const int wofs = wvi << 9;
    for (int k0 = 0; k0 < K; k0 += 32) {
        __syncthreads();
        GLL(Ah + aOff0 + k0, &lAh[wofs]);  GLL(Ah + aOff1 + k0, &lAh[2048 + wofs]);
        GLL(Al + aOff0 + k0, &lAl[wofs]);  GLL(Al + aOff1 + k0, &lAl[2048 + wofs]);
        GLL(Bh + bOff0 + k0, &lBh[wofs]);  GLL(Bh + bOff1 + k0, &lBh[2048 + wofs]);
        GLL(Bl + bOff0 + k0, &lBl[wofs]);  GLL(Bl + bOff1 + k0, &lBl[2048 + wofs]);
        __syncthreads();
        s8v ah[4], al[4], bh[4], bl[4];
#pragma unroll
        for (int i = 0; i < 4; i++) {
            const int ro = (wm * 64 + i * 16 + lid) * 32 + quad * 8;
            ah[i] = *(const s8v*)&lAh[ro];
            al[i] = *(const s8v*)&lAl[ro];
        }
#pragma unroll
        for (int j = 0; j < 4; j++) {
            const int ro = (wn * 64 + j * 16 + lid) * 32 + quad * 8;
            bh[j] = *(const s8v*)&lBh[ro];
            bl[j] = *(const s8v*)&lBl[ro];
        }
#pragma unroll
        for (int i = 0; i < 4; i++)
#pragma unroll
            for (int j = 0; j < 4; j++) {
                acc[i][j] = __builtin_amdgcn_mfma_f32_16x16x32_bf16(ah[i], bh[j], acc[i][j], 0, 0, 0);
                acc[i][j] = __builtin_amdgcn_mfma_f32_16x16x32_bf16(ah[i], bl[j], acc[i][j], 0, 0, 0);
                acc[i][j] = __builtin_amdgcn_mfma_f32_16x16x32_bf16(al[i], bh[j], acc[i][j], 0, 0, 0);
            }
    }
    const int mW = mBase + wm * 64 + quad * 4;
    const int nW = nBase + wn * 64 + lid;
#pragma unroll
    for (int j = 0; j < 4; j++) {
        const int n = nW + j * 16;
        const float* bp = (n < 1024) ? biasQ : ((n < 2048) ? biasK : biasV);
        const float bn = bp[n & 1023];
#pragma unroll
        for (int i = 0; i < 4; i++) {
            const int m = mW + i * 16;
#pragma unroll
            for (int r = 0; r < 4; r++) {
                const float v = acc[i][j][r] + bn;
                const long long o = (long long)(m + r) * ldc + n;
                if (EPI == 0) {
                    const short h = f2bf(v);
                    Ch[o] = h;
                    Cl[o] = f2bf(v - b2f(h));
                } else {
                    Cf[o] = v + resid[o];
                }
            }
        }
    }
}

// ---------------- flash attention, split hi/lo, swapped-operand softmax ----------------
// QK^T is computed as mfma(K,Q) -> S^T: each lane holds 8 scores of ONE q-row
// (q=lid, k=quad*4+r and 16+quad*4+r). Softmax is in-lane (+2 shfl_xor);
// P is packed to hi/lo bf16 in-register and redistributed to B-fragment k-order
// with bpermutes (no LDS round-trip, one fewer barrier). PV computes O^T via
// mfma(V^T, P^T) so alpha/l_run stay per-lane scalars.
// V-transpose LDS tile keeps the R1 XOR swizzle (store col srow^((sgrp&3)<<3)).
__global__ __launch_bounds__(256) void flash_attn_hl(const short* __restrict__ qkvh,
    const short* __restrict__ qkvl, const unsigned char* __restrict__ mask,
    short* __restrict__ attnh, short* __restrict__ attnl)
{
    __shared__ __align__(16) short lKh[32 * 72], lKl[32 * 72];
    __shared__ __align__(16) short lVth[64 * 40], lVtl[64 * 40];
    const int tid = threadIdx.x;
    const int lane = tid & 63, lid = lane & 15, quad = lane >> 4;
    const int w = tid >> 6;
    const int bh = blockIdx.y;
    const int b = bh >> 4, h = bh & 15;
    const int q0row = blockIdx.x * 64 + w * 16;

    // Q fragment (B-operand of swapped QK^T): lane holds Q[q=lid][d=quad*8..+8]
    const long long rowQ = (long long)(b * S_ + q0row + lid) * 3072 + h * 64;
    const s8v qh0 = *(const s8v*)&qkvh[rowQ + quad * 8];
    const s8v qh1 = *(const s8v*)&qkvh[rowQ + 32 + quad * 8];
    const s8v ql0 = *(const s8v*)&qkvl[rowQ + quad * 8];
    const s8v ql1 = *(const s8v*)&qkvl[rowQ + 32 + quad * 8];

    float m_run = -1e30f, l_run = 0.0f;
    f4v o[4];
#pragma unroll
    for (int dt = 0; dt < 4; dt++) o[dt] = f4zero();

    const unsigned char* mrow = mask + b * S_;
    const int srow = tid >> 3, sgrp = tid & 7;
    const int srcA = lid + ((quad & 1) << 5);   // bpermute source lanes
    const int srcB = srcA + 16;

    for (int c0 = 0; c0 < S_; c0 += 32) {
        __syncthreads();
        {
            const long long gk = (long long)(b * S_ + c0 + srow) * 3072 + 1024 + h * 64 + sgrp * 8;
            *(s8v*)&lKh[srow * 72 + sgrp * 8] = *(const s8v*)&qkvh[gk];
            *(s8v*)&lKl[srow * 72 + sgrp * 8] = *(const s8v*)&qkvl[gk];
            const long long gv = (long long)(b * S_ + c0 + srow) * 3072 + 2048 + h * 64 + sgrp * 8;
            const s8v vh = *(const s8v*)&qkvh[gv];
            const s8v vl = *(const s8v*)&qkvl[gv];
            const int vcol = srow ^ ((sgrp & 3) << 3);   // XOR-swizzled k-column
#pragma unroll
            for (int jj = 0; jj < 8; jj++) {
                lVth[(sgrp * 8 + jj) * 40 + vcol] = vh[jj];
                lVtl[(sgrp * 8 + jj) * 40 + vcol] = vl[jj];
            }
        }
        __syncthreads();

        f4v s0 = f4zero(), s1 = f4zero();
        {
            const int r0 = lid * 72 + quad * 8;
            const s8v kh0a = *(const s8v*)&lKh[r0];
            const s8v kh0b = *(const s8v*)&lKh[r0 + 32];
            const s8v kl0a = *(const s8v*)&lKl[r0];
            const s8v kl0b = *(const s8v*)&lKl[r0 + 32];
            s0 = __builtin_amdgcn_mfma_f32_16x16x32_bf16(kh0a, qh0, s0, 0, 0, 0);
            s0 = __builtin_amdgcn_mfma_f32_16x16x32_bf16(kh0b, qh1, s0, 0, 0, 0);
            s0 = __builtin_amdgcn_mfma_f32_16x16x32_bf16(kl0a, qh0, s0, 0, 0, 0);
            s0 = __builtin_amdgcn_mfma_f32_16x16x32_bf16(kl0b, qh1, s0, 0, 0, 0);
            s0 = __builtin_amdgcn_mfma_f32_16x16x32_bf16(kh0a, ql0, s0, 0, 0, 0);
            s0 = __builtin_amdgcn_mfma_f32_16x16x32_bf16(kh0b, ql1, s0, 0, 0, 0);
            const int r1i = (16 + lid) * 72 + quad * 8;
            const s8v kh1a = *(const s8v*)&lKh[r1i];
            const s8v kh1b = *(const s8v*)&lKh[r1i + 32];
            const s8v kl1a = *(const s8v*)&lKl[r1i];
            const s8v kl1b = *(const s8v*)&lKl[r1i + 32];
            s1 = __builtin_amdgcn_mfma_f32_16x16x32_bf16(kh1a, qh0, s1, 0, 0, 0);
            s1 = __builtin_amdgcn_mfma_f32_16x16x32_bf16(kh1b, qh1, s1, 0, 0, 0);
            s1 = __builtin_amdgcn_mfma_f32_16x16x32_bf16(kl1a, qh0, s1, 0, 0, 0);
            s1 = __builtin_amdgcn_mfma_f32_16x16x32_bf16(kl1b, qh1, s1, 0, 0, 0);
            s1 = __builtin_amdgcn_mfma_f32_16x16x32_bf16(kh1a, ql0, s1, 0, 0, 0);
            s1 = __builtin_amdgcn_mfma_f32_16x16x32_bf16(kh1b, ql1, s1, 0, 0, 0);
        }
        // lane's 8 scores: p[r] for k=quad*4+r, p[4+r] for k=16+quad*4+r; all q=lid
        const unsigned mm0 = *(const unsigned*)(mrow + c0 + quad * 4);
        const unsigned mm1 = *(const unsigned*)(mrow + c0 + 16 + quad * 4);
        float p[8];
#pragma unroll
        for (int r = 0; r < 4; r++) {
            p[r]     = ((mm0 >> (8 * r)) & 255u) ? -1e30f : s0[r] * 0.125f;
            p[4 + r] = ((mm1 >> (8 * r)) & 255u) ? -1e30f : s1[r] * 0.125f;
        }
        float mx = fmaxf(fmaxf(fmaxf(p[0], p[1]), fmaxf(p[2], p[3])),
                         fmaxf(fmaxf(p[4], p[5]), fmaxf(p[6], p[7])));
        mx = fmaxf(mx, __shfl_xor(mx, 16, 64));
        mx = fmaxf(mx, __shfl_xor(mx, 32, 64));
        const float mn = fmaxf(m_run, mx);
        const float alpha = __expf(m_run - mn);
        m_run = mn;
        float rs = 0.0f;
#pragma unroll
        for (int i = 0; i < 8; i++) { p[i] = __expf(p[i] - mn); rs += p[i]; }
        rs += __shfl_xor(rs, 16, 64);
        rs += __shfl_xor(rs, 32, 64);
        l_run = l_run * alpha + rs;
#pragma unroll
        for (int dt = 0; dt < 4; dt++)
#pragma unroll
            for (int r = 0; r < 4; r++) o[dt][r] *= alpha;

        // pack to hi/lo bf16 pairs in k-order, then redistribute to B-frag layout:
        // target quad t needs k=8t..8t+7 -> pairs (c0,c1) [t<2] or (c2,c3) [t>=2]
        // from lanes srcA=lid+32*(t&1) and srcB=srcA+16.
        unsigned c0l, c1l, c2l, c3l;
        const unsigned c0h = pk2(p[0], p[1], &c0l);
        const unsigned c1h = pk2(p[2], p[3], &c1l);
        const unsigned c2h = pk2(p[4], p[5], &c2l);
        const unsigned c3h = pk2(p[6], p[7], &c3l);
        union { s8v v; unsigned u[4]; } pah, pal;
        {
            const unsigned a0 = __shfl((int)c0h, srcA, 64), a2 = __shfl((int)c2h, srcA, 64);
            const unsigned a1 = __shfl((int)c1h, srcA, 64), a3 = __shfl((int)c3h, srcA, 64);
            const unsigned b0 = __shfl((int)c0h, srcB, 64), b2 = __shfl((int)c2h, srcB, 64);
            const unsigned b1 = __shfl((int)c1h, srcB, 64), b3 = __shfl((int)c3h, srcB, 64);
            const bool lo = (quad < 2);
            pah.u[0] = lo ? a0 : a2; pah.u[1] = lo ? a1 : a3;
            pah.u[2] = lo ? b0 : b2; pah.u[3] = lo ? b1 : b3;
        }
        {
            const unsigned a0 = __shfl((int)c0l, srcA, 64), a2 = __shfl((int)c2l, srcA, 64);
            const unsigned a1 = __shfl((int)c1l, srcA, 64), a3 = __shfl((int)c3l, srcA, 64);
            const unsigned b0 = __shfl((int)c0l, srcB, 64), b2 = __shfl((int)c2l, srcB, 64);
            const unsigned b1 = __shfl((int)c1l, srcB, 64), b3 = __shfl((int)c3l, srcB, 64);
            const bool lo = (quad < 2);
            pal.u[0] = lo ? a0 : a2; pal.u[1] = lo ? a1 : a3;
            pal.u[2] = lo ? b0 : b2; pal.u[3] = lo ? b1 : b3;
        }

        // PV as O^T: o[dt] holds O[q=lid][d=dt*16+quad*4+r]
#pragma unroll
        for (int dt = 0; dt < 4; dt++) {
            const int d = dt * 16 + lid;
            const int x3 = (dt * 2 + (lid >> 3)) & 3;          // (d>>3) & 3
            const int ro = d * 40 + ((quad ^ x3) << 3);        // de-swizzled b128 read
            const s8v bvh = *(const s8v*)&lVth[ro];
            const s8v bvl = *(const s8v*)&lVtl[ro];
            o[dt] = __builtin_amdgcn_mfma_f32_16x16x32_bf16(bvh, pah.v, o[dt], 0, 0, 0);
            o[dt] = __builtin_amdgcn_mfma_f32_16x16x32_bf16(bvl, pah.v, o[dt], 0, 0, 0);
            o[dt] = __builtin_amdgcn_mfma_f32_16x16x32_bf16(bvh, pal.v, o[dt], 0, 0, 0);
        }
    }
    const float inv_l = 1.0f / l_run;
    const long long obase = (long long)(b * S_ + q0row + lid) * D_ + h * 64 + quad * 4;
#pragma unroll
    for (int dt = 0; dt < 4; dt++) {
        short4 hh4, ll4;
        float v0 = o[dt][0] * inv_l, v1 = o[dt][1] * inv_l;
        float v2 = o[dt][2] * inv_l, v3 = o[dt][3] * inv_l;
        hh4.x = f2bf(v0); ll4.x = f2bf(v0 - b2f(hh4.x));
        hh4.y = f2bf(v1); ll4.y = f2bf(v1 - b2f(hh4.y));
        hh4.z = f2bf(v2); ll4.z = f2bf(v2 - b2f(hh4.z));
        hh4.w = f2bf(v3); ll4.w = f2bf(v3 - b2f(hh4.w));
        *(short4*)&attnh[obase + dt * 16] = hh4;
        *(short4*)&attnl[obase + dt * 16] = ll4;
    }
}

// ---------------- workspace layout (bytes) ----------------
constexpr long long SZ_DD2   = (long long)D_ * D_ * 2;
constexpr long long OFF_WQKVH = 0;
constexpr long long OFF_WQKVL = OFF_WQKVH + 3 * SZ_DD2;
constexpr long long OFF_WOH   = OFF_WQKVL + 3 * SZ_DD2;
constexpr long long OFF_WOL   = OFF_WOH + SZ_DD2;
constexpr long long OFF_W1T   = OFF_WOL + SZ_DD2;
constexpr long long OFF_W2T   = OFF_W1T + (long long)E_ * F_ * D_ * 2;
constexpr long long OFF_WS1T  = OFF_W2T + (long long)E_ * D_ * F_ * 2;
constexpr long long OFF_WS2T  = OFF_WS1T + (long long)FS_ * D_ * 2;
constexpr long long OFF_X1    = OFF_WS2T + (long long)D_ * FS_ * 2;
constexpr long long OFF_XN2   = OFF_X1 + (long long)T_ * D_ * 4;
constexpr long long OFF_TOPI  = OFF_XN2 + (long long)T_ * D_ * 2;
constexpr long long OFF_GATES = OFF_TOPI + (long long)T_ * 2 * 4;
constexpr long long OFF_POSC  = OFF_GATES + (long long)T_ * 2 * 4;
constexpr long long OFF_WVAL  = OFF_POSC + (long long)2 * T_ * 4;
constexpr long long ZONE      = OFF_WVAL + (long long)2 * T_ * 4;
// attention phase
constexpr long long OFF_XH1   = ZONE;
constexpr long long OFF_XL1   = OFF_XH1 + (long long)T_ * D_ * 2;
constexpr long long OFF_QKVH  = OFF_XL1 + (long long)T_ * D_ * 2;
constexpr long long OFF_QKVL  = OFF_QKVH + (long long)T_ * 3 * D_ * 2;
constexpr long long OFF_ATTNH = OFF_QKVL + (long long)T_ * 3 * D_ * 2;
constexpr long long OFF_ATTNL = OFF_ATTNH + (long long)T_ * D_ * 2;
// MoE phase (reuses attention zone)
constexpr long long OFF_DISP  = ZONE;
constexpr long long OFF_H     = OFF_DISP + (long long)E_ * CAP_ * D_ * 2;   // 4-expert H slab
constexpr long long OFF_EO    = OFF_H + (long long)4 * CAP_ * F_ * 2;
constexpr long long OFF_YS    = OFF_EO + (long long)E_ * CAP_ * D_ * 4;
constexpr long long OFF_HS    = ZONE;  // after experts (disp dead)

extern "C" void kernel_launch(void* const* d_in, const int* in_sizes, int n_in,
                              void* d_out, int out_size, void* d_ws, size_t ws_size,
                              hipStream_t stream)
{
    (void)in_sizes; (void)n_in; (void)out_size; (void)ws_size;
    const float* x       = (const float*)d_in[0];
    const unsigned char* mask = (const unsigned char*)d_in[1];
    const float* ln1g    = (const float*)d_in[2];
    const float* ln1b    = (const float*)d_in[3];
    const float* wq      = (const float*)d_in[4];
    const float* bq      = (const float*)d_in[5];
    const float* wk      = (const float*)d_in[6];
    const float* bk      = (const float*)d_in[7];
    const float* wvp     = (const float*)d_in[8];
    const float* bvv     = (const float*)d_in[9];
    const float* wo      = (const float*)d_in[10];
    const float* bo      = (const float*)d_in[11];
    const float* ln2g    = (const float*)d_in[12];
    const float* ln2b    = (const float*)d_in[13];
    const float* wrouter = (const float*)d_in[14];
    const float* w1      = (const float*)d_in[15];
    const float* b1      = (const float*)d_in[16];
    const float* w2      = (const float*)d_in[17];
    const float* b2      = (const float*)d_in[18];
    const float* ws1     = (const float*)d_in[19];
    const float* bs1     = (const float*)d_in[20];
    const float* ws2     = (const float*)d_in[21];
    const float* bs2     = (const float*)d_in[22];
    float* out = (float*)d_out;
    char* ws = (char*)d_ws;

    short* wqkvh = (short*)(ws + OFF_WQKVH);
    short* wqkvl = (short*)(ws + OFF_WQKVL);
    short* woh   = (short*)(ws + OFF_WOH);
    short* wol   = (short*)(ws + OFF_WOL);
    short* w1T   = (short*)(ws + OFF_W1T);
    short* w2T   = (short*)(ws + OFF_W2T);
    short* ws1T  = (short*)(ws + OFF_WS1T);
    short* ws2T  = (short*)(ws + OFF_WS2T);
    float* x1    = (float*)(ws + OFF_X1);
    short* xn2   = (short*)(ws + OFF_XN2);
    int*   topi  = (int*)(ws + OFF_TOPI);
    float* gates = (float*)(ws + OFF_GATES);
    int*   posc  = (int*)(ws + OFF_POSC);
    float* wval  = (float*)(ws + OFF_WVAL);
    short* xh1   = (short*)(ws + OFF_XH1);
    short* xl1   = (short*)(ws + OFF_XL1);
    short* qkvh  = (short*)(ws + OFF_QKVH);
    short* qkvl  = (short*)(ws + OFF_QKVL);
    short* attnh = (short*)(ws + OFF_ATTNH);
    short* attnl = (short*)(ws + OFF_ATTNL);
    short* disp  = (short*)(ws + OFF_DISP);
    short* hbuf  = (short*)(ws + OFF_H);
    float* eo    = (float*)(ws + OFF_EO);
    short* hs    = (short*)(ws + OFF_HS);
    float* ysb   = (float*)(ws + OFF_YS);

    const dim3 tb(256);
    transcvt2<<<dim3(32, 32), tb, 0, stream>>>(wq,  wqkvh,               wqkvl,               1024, 1024);
    transcvt2<<<dim3(32, 32), tb, 0, stream>>>(wk,  wqkvh + 1024 * 1024, wqkvl + 1024 * 1024, 1024, 1024);
    transcvt2<<<dim3(32, 32), tb, 0, stream>>>(wvp, wqkvh + 2 * 1024 * 1024, wqkvl + 2 * 1024 * 1024, 1024, 1024);
    transcvt2<<<dim3(32, 32), tb, 0, stream>>>(wo,  woh, wol, 1024, 1024);
    transcvt<<<dim3(128, 32, 8), tb, 0, stream>>>(w1, w1T, 1024, 4096);
    transcvt<<<dim3(32, 128, 8), tb, 0, stream>>>(w2, w2T, 4096, 1024);
    transcvt<<<dim3(64, 32, 1), tb, 0, stream>>>(ws1, ws1T, 1024, 2048);
    transcvt<<<dim3(32, 64, 1), tb, 0, stream>>>(ws2, ws2T, 2048, 1024);

    ln1_split<<<T_, 256, 0, stream>>>(x, ln1g, ln1b, xh1, xl1);

    // fused QKV: B = [3072,1024] (wq^T|wk^T|wv^T contiguous), per-segment bias
    gemm_hl<0><<<dim3(24, 64), 256, 0, stream>>>(xh1, xl1, wqkvh, wqkvl,
        bq, bk, bvv, nullptr, qkvh, qkvl, nullptr, T_, 3072, 1024, 3072);

    flash_attn_hl<<<dim3(32, 64), 256, 0, stream>>>(qkvh, qkvl, mask, attnh, attnl);

    gemm_hl<1><<<dim3(8, 64), 256, 0, stream>>>(attnh, attnl, woh, wol,
        bo, bo, bo, x, nullptr, nullptr, x1, T_, 1024, 1024, 1024);

    ln2_router_kernel<<<T_, 256, 0, stream>>>(x1, ln2g, ln2b, wrouter, xn2, topi, gates);
    route_scan<<<1, 256, 0, stream>>>(topi, gates, posc, wval);
    dispatch_kernel<<<2 * T_, 128, 0, stream>>>(xn2, topi, posc, disp);

    // experts batched over blockIdx.z in 2 groups of 4 (H slab = 4 experts)
    for (int g = 0; g < 2; g++) {
        const long long e0 = (long long)g * 4;
        gemm_btz<1><<<dim3(32, 20, 4), 256, 0, stream>>>(
            disp + e0 * CAP_ * D_, w1T + e0 * F_ * D_, b1 + e0 * F_, hbuf,
            CAP_, F_, 1024, F_,
            (long long)CAP_ * D_, (long long)F_ * D_, (long long)F_, (long long)CAP_ * F_);
        gemm_btz<2><<<dim3(8, 20, 4), 256, 0, stream>>>(
            hbuf, w2T + e0 * D_ * F_, b2 + e0 * D_, eo + e0 * CAP_ * D_,
            CAP_, 1024, F_, 1024,
            (long long)CAP_ * F_, (long long)D_ * F_, (long long)D_, (long long)CAP_ * D_);
    }

    gemm_btz<1><<<dim3(16, 64, 1), 256, 0, stream>>>(xn2, ws1T, bs1, hs,
        T_, FS_, 1024, FS_, 0, 0, 0, 0);
    gemm_btz<2><<<dim3(8, 64, 1), 256, 0, stream>>>(hs, ws2T, bs2, ysb,
        T_, 1024, FS_, 1024, 0, 0, 0, 0);

    combine_kernel<<<T_, 256, 0, stream>>>(x1, ysb, eo, topi, posc, wval, out);
}

// Round 4
// 1891.037 us; speedup vs baseline: 1.4819x; 1.0197x over previous
//
#include <hip/hip_runtime.h>
#include <hip/hip_bf16.h>
#include <stdint.h>

#define D_ 1024
#define S_ 2048
#define B_ 4
#define H_ 16
#define T_ 8192
#define E_ 8
#define CAP_ 2560
#define F_ 4096
#define FS_ 2048

typedef __attribute__((ext_vector_type(8))) short s8v;
typedef __attribute__((ext_vector_type(4))) float f4v;

#define GLL(gp, lp) __builtin_amdgcn_global_load_lds( \
    (const __attribute__((address_space(1))) unsigned int*)(gp), \
    (__attribute__((address_space(3))) unsigned int*)(lp), 16, 0, 0)

__device__ inline short f2bf(float f) {
    union { float f; unsigned u; } v; v.f = f;
    unsigned r = (v.u + 0x7fffu + ((v.u >> 16) & 1u)) >> 16;
    return (short)(r & 0xffffu);
}
__device__ inline float b2f(short h) {
    union { unsigned u; float f; } v; v.u = ((unsigned)(unsigned short)h) << 16; return v.f;
}
__device__ inline float gelu_f(float x) {
    return 0.5f * x * (1.0f + erff(x * 0.7071067811865475f));
}
__device__ inline f4v f4zero() { f4v z; z[0]=0.f; z[1]=0.f; z[2]=0.f; z[3]=0.f; return z; }

// pack (a,b) -> hi-plane bf16 pair; lo-plane residual pair written to *lo
__device__ inline unsigned pk2(float a, float b, unsigned* lo) {
    const short ha = f2bf(a), hb = f2bf(b);
    const short la = f2bf(a - b2f(ha)), lb = f2bf(b - b2f(hb));
    *lo = ((unsigned)(unsigned short)lb << 16) | (unsigned)(unsigned short)la;
    return ((unsigned)(unsigned short)hb << 16) | (unsigned)(unsigned short)ha;
}

// ---------------- transpose + fp32->bf16 (single plane, MoE weights) ----------------
__global__ __launch_bounds__(256) void transcvt(const float* __restrict__ in,
                                                short* __restrict__ out, int R, int C)
{
    __shared__ float tile[32][33];
    const int tid = threadIdx.x;
    const int tx = tid & 31, ty = tid >> 5;
    const long long ib = (long long)blockIdx.z * R * C;
    const int r0 = blockIdx.y * 32, c0 = blockIdx.x * 32;
#pragma unroll
    for (int i = 0; i < 4; i++)
        tile[ty + i * 8][tx] = in[ib + (long long)(r0 + ty + i * 8) * C + c0 + tx];
    __syncthreads();
#pragma unroll
    for (int i = 0; i < 4; i++)
        out[ib + (long long)(c0 + ty + i * 8) * R + r0 + tx] = f2bf(tile[tx][ty + i * 8]);
}

// ---------------- transpose + hi/lo split (attention weights) ----------------
__global__ __launch_bounds__(256) void transcvt2(const float* __restrict__ in,
    short* __restrict__ oh, short* __restrict__ ol, int R, int C)
{
    __shared__ float tile[32][33];
    const int tid = threadIdx.x;
    const int tx = tid & 31, ty = tid >> 5;
    const int r0 = blockIdx.y * 32, c0 = blockIdx.x * 32;
#pragma unroll
    for (int i = 0; i < 4; i++)
        tile[ty + i * 8][tx] = in[(long long)(r0 + ty + i * 8) * C + c0 + tx];
    __syncthreads();
#pragma unroll
    for (int i = 0; i < 4; i++) {
        const float v = tile[tx][ty + i * 8];
        const short h = f2bf(v);
        const long long o = (long long)(c0 + ty + i * 8) * R + r0 + tx;
        oh[o] = h;
        ol[o] = f2bf(v - b2f(h));
    }
}

// ---------------- LN1: fp32 x -> hi/lo bf16 planes ----------------
__global__ __launch_bounds__(256) void ln1_split(const float* __restrict__ x,
    const float* __restrict__ g, const float* __restrict__ bta,
    short* __restrict__ xh, short* __restrict__ xl)
{
    const int t = blockIdx.x, tid = threadIdx.x;
    const float4 v = ((const float4*)(x + (long long)t * D_))[tid];
    float s1 = v.x + v.y + v.z + v.w;
    float s2 = v.x * v.x + v.y * v.y + v.z * v.z + v.w * v.w;
#pragma unroll
    for (int off = 32; off; off >>= 1) { s1 += __shfl_xor(s1, off, 64); s2 += __shfl_xor(s2, off, 64); }
    __shared__ float r1[4], r2[4];
    if ((tid & 63) == 0) { r1[tid >> 6] = s1; r2[tid >> 6] = s2; }
    __syncthreads();
    s1 = r1[0] + r1[1] + r1[2] + r1[3];
    s2 = r2[0] + r2[1] + r2[2] + r2[3];
    const float mu = s1 * (1.0f / D_);
    const float var = s2 * (1.0f / D_) - mu * mu;
    const float rs = rsqrtf(var + 1e-5f);
    const float4 gv = ((const float4*)g)[tid];
    const float4 bv = ((const float4*)bta)[tid];
    float xn[4];
    xn[0] = (v.x - mu) * rs * gv.x + bv.x;
    xn[1] = (v.y - mu) * rs * gv.y + bv.y;
    xn[2] = (v.z - mu) * rs * gv.z + bv.z;
    xn[3] = (v.w - mu) * rs * gv.w + bv.w;
    short4 hh, ll;
    hh.x = f2bf(xn[0]); ll.x = f2bf(xn[0] - b2f(hh.x));
    hh.y = f2bf(xn[1]); ll.y = f2bf(xn[1] - b2f(hh.y));
    hh.z = f2bf(xn[2]); ll.z = f2bf(xn[2] - b2f(hh.z));
    hh.w = f2bf(xn[3]); ll.w = f2bf(xn[3] - b2f(hh.w));
    ((short4*)(xh + (long long)t * D_))[tid] = hh;
    ((short4*)(xl + (long long)t * D_))[tid] = ll;
}

// ---------------- LN2 + router (fp32 logits, bf16 xn out) ----------------
__global__ __launch_bounds__(256) void ln2_router_kernel(const float* __restrict__ x,
    const float* __restrict__ g, const float* __restrict__ bta, const float* __restrict__ wr,
    short* __restrict__ xo, int* __restrict__ topi, float* __restrict__ gates)
{
    const int t = blockIdx.x, tid = threadIdx.x;
    const float4 v = ((const float4*)(x + (long long)t * D_))[tid];
    float s1 = v.x + v.y + v.z + v.w;
    float s2 = v.x * v.x + v.y * v.y + v.z * v.z + v.w * v.w;
#pragma unroll
    for (int off = 32; off; off >>= 1) { s1 += __shfl_xor(s1, off, 64); s2 += __shfl_xor(s2, off, 64); }
    __shared__ float r1[4], r2[4];
    if ((tid & 63) == 0) { r1[tid >> 6] = s1; r2[tid >> 6] = s2; }
    __syncthreads();
    s1 = r1[0] + r1[1] + r1[2] + r1[3];
    s2 = r2[0] + r2[1] + r2[2] + r2[3];
    const float mu = s1 * (1.0f / D_);
    const float var = s2 * (1.0f / D_) - mu * mu;
    const float rs = rsqrtf(var + 1e-5f);
    const float4 gv = ((const float4*)g)[tid];
    const float4 bv = ((const float4*)bta)[tid];
    float xn[4];
    xn[0] = (v.x - mu) * rs * gv.x + bv.x;
    xn[1] = (v.y - mu) * rs * gv.y + bv.y;
    xn[2] = (v.z - mu) * rs * gv.z + bv.z;
    xn[3] = (v.w - mu) * rs * gv.w + bv.w;
    short4 o;
    o.x = f2bf(xn[0]); o.y = f2bf(xn[1]); o.z = f2bf(xn[2]); o.w = f2bf(xn[3]);
    ((short4*)(xo + (long long)t * D_))[tid] = o;

    float a8[8] = {0, 0, 0, 0, 0, 0, 0, 0};
#pragma unroll
    for (int q = 0; q < 4; q++) {
        const int d = tid * 4 + q;
        const float4 w0 = ((const float4*)(wr + d * 8))[0];
        const float4 w1 = ((const float4*)(wr + d * 8))[1];
        a8[0] += xn[q] * w0.x; a8[1] += xn[q] * w0.y; a8[2] += xn[q] * w0.z; a8[3] += xn[q] * w0.w;
        a8[4] += xn[q] * w1.x; a8[5] += xn[q] * w1.y; a8[6] += xn[q] * w1.z; a8[7] += xn[q] * w1.w;
    }
    __shared__ float lred[32];
#pragma unroll
    for (int e = 0; e < 8; e++) {
        float vv = a8[e];
#pragma unroll
        for (int off = 32; off; off >>= 1) vv += __shfl_xor(vv, off, 64);
        if ((tid & 63) == 0) lred[(tid >> 6) * 8 + e] = vv;
    }
    __syncthreads();
    if (tid == 0) {
        float lg[8];
#pragma unroll
        for (int e = 0; e < 8; e++) lg[e] = lred[e] + lred[8 + e] + lred[16 + e] + lred[24 + e];
        int e0 = 0;
        for (int e = 1; e < 8; e++) if (lg[e] > lg[e0]) e0 = e;
        int e1 = (e0 == 0) ? 1 : 0;
        for (int e = 0; e < 8; e++) if (e != e0 && lg[e] > lg[e1]) e1 = e;
        const float mx = lg[e0];
        float den = 0.f;
        for (int e = 0; e < 8; e++) den += expf(lg[e] - mx);
        const float p0 = expf(lg[e0] - mx) / den;
        const float p1 = expf(lg[e1] - mx) / den;
        const float inv = 1.0f / (p0 + p1);
        topi[t * 2] = e0; topi[t * 2 + 1] = e1;
        gates[t * 2] = p0 * inv; gates[t * 2 + 1] = p1 * inv;
    }
}

// ---------------- slot-major capacity scan ----------------
__global__ __launch_bounds__(256) void route_scan(const int* __restrict__ topi,
    const float* __restrict__ gates, int* __restrict__ posc, float* __restrict__ wv)
{
    const int tid = threadIdx.x;
    const int w = tid >> 6, lane = tid & 63;
    __shared__ int wsum[4 * 8];
    int cnt[8] = {0, 0, 0, 0, 0, 0, 0, 0};
    const int base_r = tid * 64;
    for (int i = 0; i < 64; i++) {
        const int r = base_r + i;
        const int k = r >> 13, t = r & (T_ - 1);
        cnt[topi[t * 2 + k]]++;
    }
    int excl[8];
#pragma unroll
    for (int e = 0; e < 8; e++) {
        int x = cnt[e];
#pragma unroll
        for (int off = 1; off < 64; off <<= 1) {
            int y = __shfl_up(x, off, 64);
            if (lane >= off) x += y;
        }
        excl[e] = x - cnt[e];
        if (lane == 63) wsum[w * 8 + e] = x;
    }
    __syncthreads();
    int pos[8];
#pragma unroll
    for (int e = 0; e < 8; e++) {
        int s = 0;
        for (int ww = 0; ww < 4; ww++) if (ww < w) s += wsum[ww * 8 + e];
        pos[e] = s + excl[e];
    }
    for (int i = 0; i < 64; i++) {
        const int r = base_r + i;
        const int k = r >> 13, t = r & (T_ - 1);
        const int e = topi[t * 2 + k];
        const int p = pos[e]++;
        const bool keep = p < CAP_;
        posc[r] = keep ? p : -1;
        wv[r] = keep ? gates[t * 2 + k] : 0.0f;
    }
}

// ---------------- dispatch copy ----------------
__global__ __launch_bounds__(128) void dispatch_kernel(const short* __restrict__ xn2,
    const int* __restrict__ topi, const int* __restrict__ posc, short* __restrict__ disp)
{
    const int r = blockIdx.x;
    const int p = posc[r];
    if (p < 0) return;
    const int k = r >> 13, t = r & (T_ - 1);
    const int e = topi[t * 2 + k];
    const int tid = threadIdx.x;
    *(s8v*)&disp[((long long)e * CAP_ + p) * D_ + tid * 8] =
        *(const s8v*)&xn2[(long long)t * D_ + tid * 8];
}

// ---------------- combine ----------------
__global__ __launch_bounds__(256) void combine_kernel(const float* __restrict__ x1,
    const float* __restrict__ ys, const float* __restrict__ eo,
    const int* __restrict__ topi, const int* __restrict__ posc,
    const float* __restrict__ wv, float* __restrict__ out)
{
    const int t = blockIdx.x, tid = threadIdx.x;
    float4 a = *(const float4*)&x1[(long long)t * D_ + tid * 4];
    const float4 b = *(const float4*)&ys[(long long)t * D_ + tid * 4];
    a.x += b.x; a.y += b.y; a.z += b.z; a.w += b.w;
#pragma unroll
    for (int k = 0; k < 2; k++) {
        const int r = k * T_ + t;
        const int p = posc[r];
        if (p >= 0) {
            const int e = topi[t * 2 + k];
            const float wt = wv[r];
            const float4 c = *(const float4*)&eo[((long long)e * CAP_ + p) * D_ + tid * 4];
            a.x += wt * c.x; a.y += wt * c.y; a.z += wt * c.z; a.w += wt * c.w;
        }
    }
    *(float4*)&out[(long long)t * D_ + tid * 4] = a;
}

// ---------------- single-plane bf16 GEMM, z-batched (MoE + shared path) ----------------
// EPI: 1 = bias+gelu -> bf16 ; 2 = bias -> f32
template <int EPI>
__global__ __launch_bounds__(256) void gemm_btz(
    const short* __restrict__ A, const short* __restrict__ Bt,
    const float* __restrict__ bias, void* __restrict__ Cout,
    int M, int N, int K, int ldc,
    long long sA, long long sB, long long sBias, long long sC)
{
    __shared__ __align__(16) short lA[128 * 32];
    __shared__ __align__(16) short lB[128 * 32];
    const int z = blockIdx.z;
    A += (long long)z * sA;
    Bt += (long long)z * sB;
    bias += (long long)z * sBias;
    const int tid = threadIdx.x;
    const int wvi = tid >> 6, lane = tid & 63, lid = lane & 15, quad = lane >> 4;
    const int wm = wvi >> 1, wn = wvi & 1;
    const int mBase = blockIdx.y * 128, nBase = blockIdx.x * 128;
    f4v acc[4][4];
#pragma unroll
    for (int i = 0; i < 4; i++)
#pragma unroll
        for (int j = 0; j < 4; j++) acc[i][j] = f4zero();
    const long long aOff0 = (long long)(mBase + (tid >> 2)) * K + (tid & 3) * 8;
    const long long aOff1 = aOff0 + 64LL * K;
    const long long bOff0 = (long long)(nBase + (tid >> 2)) * K + (tid & 3) * 8;
    const long long bOff1 = bOff0 + 64LL * K;
    const int wofs = wvi << 9;
    for (int k0 = 0; k0 < K; k0 += 32) {
        __syncthreads();
        GLL(A + aOff0 + k0, &lA[wofs]);  GLL(A + aOff1 + k0, &lA[2048 + wofs]);
        GLL(Bt + bOff0 + k0, &lB[wofs]); GLL(Bt + bOff1 + k0, &lB[2048 + wofs]);
        __syncthreads();
        s8v af[4], bf[4];
#pragma unroll
        for (int i = 0; i < 4; i++)
            af[i] = *(const s8v*)&lA[(wm * 64 + i * 16 + lid) * 32 + quad * 8];
#pragma unroll
        for (int j = 0; j < 4; j++)
            bf[j] = *(const s8v*)&lB[(wn * 64 + j * 16 + lid) * 32 + quad * 8];
#pragma unroll
        for (int i = 0; i < 4; i++)
#pragma unroll
            for (int j = 0; j < 4; j++)
                acc[i][j] = __builtin_amdgcn_mfma_f32_16x16x32_bf16(af[i], bf[j], acc[i][j], 0, 0, 0);
    }
    const int mW = mBase + wm * 64 + quad * 4;
    const int nW = nBase + wn * 64 + lid;
    short* Cs = (short*)Cout + (long long)z * sC;
    float* Cf = (float*)Cout + (long long)z * sC;
#pragma unroll
    for (int j = 0; j < 4; j++) {
        const int n = nW + j * 16;
        const float bn = bias[n];
#pragma unroll
        for (int i = 0; i < 4; i++) {
            const int m = mW + i * 16;
#pragma unroll
            for (int r = 0; r < 4; r++) {
                float v = acc[i][j][r] + bn;
                if (EPI == 1) { v = gelu_f(v); Cs[(long long)(m + r) * ldc + n] = f2bf(v); }
                else          { Cf[(long long)(m + r) * ldc + n] = v; }
            }
        }
    }
}

// ---------------- split hi/lo GEMM: C = (Ah+Al) * (Bh+Bl)^T  (3-term) ----------------
// EPI: 0 = bias -> dual bf16 planes ; 1 = bias + resid -> f32
// Bias is selected per 1024-column segment (allows fused QKV: N=3072).
template <int EPI>
__global__ __launch_bounds__(256) void gemm_hl(
    const short* __restrict__ Ah, const short* __restrict__ Al,
    const short* __restrict__ Bh, const short* __restrict__ Bl,
    const float* __restrict__ biasQ, const float* __restrict__ biasK,
    const float* __restrict__ biasV, const float* __restrict__ resid,
    short* __restrict__ Ch, short* __restrict__ Cl, float* __restrict__ Cf,
    int M, int N, int K, int ldc)
{
    __shared__ __align__(16) short lAh[4096], lAl[4096], lBh[4096], lBl[4096];
    const int tid = threadIdx.x;
    const int wvi = tid >> 6, lane = tid & 63, lid = lane & 15, quad = lane >> 4;
    const int wm = wvi >> 1, wn = wvi & 1;
    const int mBase = blockIdx.y * 128, nBase = blockIdx.x * 128;
    f4v acc[4][4];
#pragma unroll
    for (int i = 0; i < 4; i++)
#pragma unroll
        for (int j = 0; j < 4; j++) acc[i][j] = f4zero();
    const long long aOff0 = (long long)(mBase + (tid >> 2)) * K + (tid & 3) * 8;
    const long long aOff1 = aOff0 + 64LL * K;
    const long long bOff0 = (long long)(nBase + (tid >> 2)) * K + (tid & 3) * 8;
    const long long bOff1 = bOff0 + 64LL * K;
    const int wofs = wvi << 9;
    for (int k0 = 0; k0 < K; k0 += 32) {
        __syncthreads();
        GLL(Ah + aOff0 + k0, &lAh[wofs]);  GLL(Ah + aOff1 + k0, &lAh[2048 + wofs]);
        GLL(Al + aOff0 + k0, &lAl[wofs]);  GLL(Al + aOff1 + k0, &lAl[2048 + wofs]);
        GLL(Bh + bOff0 + k0, &lBh[wofs]);  GLL(Bh + bOff1 + k0, &lBh[2048 + wofs]);
        GLL(Bl + bOff0 + k0, &lBl[wofs]);  GLL(Bl + bOff1 + k0, &lBl[2048 + wofs]);
        __syncthreads();
        s8v ah[4], al[4], bh[4], bl[4];
#pragma unroll
        for (int i = 0; i < 4; i++) {
            const int ro = (wm * 64 + i * 16 + lid) * 32 + quad * 8;
            ah[i] = *(const s8v*)&lAh[ro];
            al[i] = *(const s8v*)&lAl[ro];
        }
#pragma unroll
        for (int j = 0; j < 4; j++) {
            const int ro = (wn * 64 + j * 16 + lid) * 32 + quad * 8;
            bh[j] = *(const s8v*)&lBh[ro];
            bl[j] = *(const s8v*)&lBl[ro];
        }
#pragma unroll
        for (int i = 0; i < 4; i++)
#pragma unroll
            for (int j = 0; j < 4; j++) {
                acc[i][j] = __builtin_amdgcn_mfma_f32_16x16x32_bf16(ah[i], bh[j], acc[i][j], 0, 0, 0);
                acc[i][j] = __builtin_amdgcn_mfma_f32_16x16x32_bf16(ah[i], bl[j], acc[i][j], 0, 0, 0);
                acc[i][j] = __builtin_amdgcn_mfma_f32_16x16x32_bf16(al[i], bh[j], acc[i][j], 0, 0, 0);
            }
    }
    const int mW = mBase + wm * 64 + quad * 4;
    const int nW = nBase + wn * 64 + lid;
#pragma unroll
    for (int j = 0; j < 4; j++) {
        const int n = nW + j * 16;
        const float* bp = (n < 1024) ? biasQ : ((n < 2048) ? biasK : biasV);
        const float bn = bp[n & 1023];
#pragma unroll
        for (int i = 0; i < 4; i++) {
            const int m = mW + i * 16;
#pragma unroll
            for (int r = 0; r < 4; r++) {
                const float v = acc[i][j][r] + bn;
                const long long o = (long long)(m + r) * ldc + n;
                if (EPI == 0) {
                    const short h = f2bf(v);
                    Ch[o] = h;
                    Cl[o] = f2bf(v - b2f(h));
                } else {
                    Cf[o] = v + resid[o];
                }
            }
        }
    }
}

// ---------------- flash attention, split hi/lo, swapped-operand softmax ----------------
// R3: swapped QK^T (mfma(K,Q) -> S^T), in-lane softmax, register P redistribution.
// R4 adds: T14 async-STAGE (issue K/V loads for tile t+1 after barrier #2 so the
// HBM/L2 latency hides under tile t's compute), T13 defer-max (skip O-rescale when
// __all(mx - m_run <= 8); P bounded by e^8, fp32 accum safe), T5 setprio around
// both MFMA clusters. V-transpose LDS keeps the R1 XOR swizzle.
__global__ __launch_bounds__(256) void flash_attn_hl(const short* __restrict__ qkvh,
    const short* __restrict__ qkvl, const unsigned char* __restrict__ mask,
    short* __restrict__ attnh, short* __restrict__ attnl)
{
    __shared__ __align__(16) short lKh[32 * 72], lKl[32 * 72];
    __shared__ __align__(16) short lVth[64 * 40], lVtl[64 * 40];
    const int tid = threadIdx.x;
    const int lane = tid & 63, lid = lane & 15, quad = lane >> 4;
    const int w = tid >> 6;
    const int bh = blockIdx.y;
    const int b = bh >> 4, h = bh & 15;
    const int q0row = blockIdx.x * 64 + w * 16;

    // Q fragment (B-operand of swapped QK^T): lane holds Q[q=lid][d=quad*8..+8]
    const long long rowQ = (long long)(b * S_ + q0row + lid) * 3072 + h * 64;
    const s8v qh0 = *(const s8v*)&qkvh[rowQ + quad * 8];
    const s8v qh1 = *(const s8v*)&qkvh[rowQ + 32 + quad * 8];
    const s8v ql0 = *(const s8v*)&qkvl[rowQ + quad * 8];
    const s8v ql1 = *(const s8v*)&qkvl[rowQ + 32 + quad * 8];

    float m_run = -1e30f, l_run = 0.0f;
    f4v o[4];
#pragma unroll
    for (int dt = 0; dt < 4; dt++) o[dt] = f4zero();

    const unsigned char* mrow = mask + b * S_;
    const int srow = tid >> 3, sgrp = tid & 7;
    const int vcol = srow ^ ((sgrp & 3) << 3);   // XOR-swizzled k-column (store side)
    const int srcA = lid + ((quad & 1) << 5);    // bpermute source lanes
    const int srcB = srcA + 16;

    // T14 prologue: issue loads for tile 0
    s8v kh_r, kl_r, vh_r, vl_r;
    {
        const long long gk = (long long)(b * S_ + srow) * 3072 + 1024 + h * 64 + sgrp * 8;
        kh_r = *(const s8v*)&qkvh[gk];
        kl_r = *(const s8v*)&qkvl[gk];
        vh_r = *(const s8v*)&qkvh[gk + 1024];
        vl_r = *(const s8v*)&qkvl[gk + 1024];
    }

    for (int c0 = 0; c0 < S_; c0 += 32) {
        __syncthreads();                 // prev iter done reading LDS
        {
            *(s8v*)&lKh[srow * 72 + sgrp * 8] = kh_r;
            *(s8v*)&lKl[srow * 72 + sgrp * 8] = kl_r;
#pragma unroll
            for (int jj = 0; jj < 8; jj++) {
                lVth[(sgrp * 8 + jj) * 40 + vcol] = vh_r[jj];
                lVtl[(sgrp * 8 + jj) * 40 + vcol] = vl_r[jj];
            }
        }
        __syncthreads();
        // T14: issue next tile's loads now; latency hides under this tile's compute
        if (c0 + 32 < S_) {
            const long long gk = (long long)(b * S_ + c0 + 32 + srow) * 3072 + 1024 + h * 64 + sgrp * 8;
            kh_r = *(const s8v*)&qkvh[gk];
            kl_r = *(const s8v*)&qkvl[gk];
            vh_r = *(const s8v*)&qkvh[gk + 1024];
            vl_r = *(const s8v*)&qkvl[gk + 1024];
        }

        f4v s0 = f4zero(), s1 = f4zero();
        {
            const int r0 = lid * 72 + quad * 8;
            const s8v kh0a = *(const s8v*)&lKh[r0];
            const s8v kh0b = *(const s8v*)&lKh[r0 + 32];
            const s8v kl0a = *(const s8v*)&lKl[r0];
            const s8v kl0b = *(const s8v*)&lKl[r0 + 32];
            const int r1i = (16 + lid) * 72 + quad * 8;
            const s8v kh1a = *(const s8v*)&lKh[r1i];
            const s8v kh1b = *(const s8v*)&lKh[r1i + 32];
            const s8v kl1a = *(const s8v*)&lKl[r1i];
            const s8v kl1b = *(const s8v*)&lKl[r1i + 32];
            __builtin_amdgcn_s_setprio(1);
            s0 = __builtin_amdgcn_mfma_f32_16x16x32_bf16(kh0a, qh0, s0, 0, 0, 0);
            s0 = __builtin_amdgcn_mfma_f32_16x16x32_bf16(kh0b, qh1, s0, 0, 0, 0);
            s0 = __builtin_amdgcn_mfma_f32_16x16x32_bf16(kl0a, qh0, s0, 0, 0, 0);
            s0 = __builtin_amdgcn_mfma_f32_16x16x32_bf16(kl0b, qh1, s0, 0, 0, 0);
            s0 = __builtin_amdgcn_mfma_f32_16x16x32_bf16(kh0a, ql0, s0, 0, 0, 0);
            s0 = __builtin_amdgcn_mfma_f32_16x16x32_bf16(kh0b, ql1, s0, 0, 0, 0);
            s1 = __builtin_amdgcn_mfma_f32_16x16x32_bf16(kh1a, qh0, s1, 0, 0, 0);
            s1 = __builtin_amdgcn_mfma_f32_16x16x32_bf16(kh1b, qh1, s1, 0, 0, 0);
            s1 = __builtin_amdgcn_mfma_f32_16x16x32_bf16(kl1a, qh0, s1, 0, 0, 0);
            s1 = __builtin_amdgcn_mfma_f32_16x16x32_bf16(kl1b, qh1, s1, 0, 0, 0);
            s1 = __builtin_amdgcn_mfma_f32_16x16x32_bf16(kh1a, ql0, s1, 0, 0, 0);
            s1 = __builtin_amdgcn_mfma_f32_16x16x32_bf16(kh1b, ql1, s1, 0, 0, 0);
            __builtin_amdgcn_s_setprio(0);
        }
        // lane's 8 scores: p[r] for k=quad*4+r, p[4+r] for k=16+quad*4+r; all q=lid
        const unsigned mm0 = *(const unsigned*)(mrow + c0 + quad * 4);
        const unsigned mm1 = *(const unsigned*)(mrow + c0 + 16 + quad * 4);
        float p[8];
#pragma unroll
        for (int r = 0; r < 4; r++) {
            p[r]     = ((mm0 >> (8 * r)) & 255u) ? -1e30f : s0[r] * 0.125f;
            p[4 + r] = ((mm1 >> (8 * r)) & 255u) ? -1e30f : s1[r] * 0.125f;
        }
        float mx = fmaxf(fmaxf(fmaxf(p[0], p[1]), fmaxf(p[2], p[3])),
                         fmaxf(fmaxf(p[4], p[5]), fmaxf(p[6], p[7])));
        mx = fmaxf(mx, __shfl_xor(mx, 16, 64));
        mx = fmaxf(mx, __shfl_xor(mx, 32, 64));
        // T13 defer-max: skip rescale when per-row growth <= 8 across the wave
        if (__all(mx - m_run <= 8.0f)) {
            float rs = 0.0f;
#pragma unroll
            for (int i = 0; i < 8; i++) { p[i] = __expf(p[i] - m_run); rs += p[i]; }
            rs += __shfl_xor(rs, 16, 64);
            rs += __shfl_xor(rs, 32, 64);
            l_run += rs;
        } else {
            const float mn = fmaxf(m_run, mx);
            const float alpha = __expf(m_run - mn);
            m_run = mn;
            float rs = 0.0f;
#pragma unroll
            for (int i = 0; i < 8; i++) { p[i] = __expf(p[i] - mn); rs += p[i]; }
            rs += __shfl_xor(rs, 16, 64);
            rs += __shfl_xor(rs, 32, 64);
            l_run = l_run * alpha + rs;
#pragma unroll
            for (int dt = 0; dt < 4; dt++)
#pragma unroll
                for (int r = 0; r < 4; r++) o[dt][r] *= alpha;
        }

        // pack to hi/lo bf16 pairs in k-order, then redistribute to B-frag layout:
        // target quad t needs k=8t..8t+7 -> pairs (c0,c1) [t<2] or (c2,c3) [t>=2]
        // from lanes srcA=lid+32*(t&1) and srcB=srcA+16.
        unsigned c0l, c1l, c2l, c3l;
        const unsigned c0h = pk2(p[0], p[1], &c0l);
        const unsigned c1h = pk2(p[2], p[3], &c1l);
        const unsigned c2h = pk2(p[4], p[5], &c2l);
        const unsigned c3h = pk2(p[6], p[7], &c3l);
        union { s8v v; unsigned u[4]; } pah, pal;
        {
            const unsigned a0 = __shfl((int)c0h, srcA, 64), a2 = __shfl((int)c2h, srcA, 64);
            const unsigned a1 = __shfl((int)c1h, srcA, 64), a3 = __shfl((int)c3h, srcA, 64);
            const unsigned b0 = __shfl((int)c0h, srcB, 64), b2 = __shfl((int)c2h, srcB, 64);
            const unsigned b1 = __shfl((int)c1h, srcB, 64), b3 = __shfl((int)c3h, srcB, 64);
            const bool lo = (quad < 2);
            pah.u[0] = lo ? a0 : a2; pah.u[1] = lo ? a1 : a3;
            pah.u[2] = lo ? b0 : b2; pah.u[3] = lo ? b1 : b3;
        }
        {
            const unsigned a0 = __shfl((int)c0l, srcA, 64), a2 = __shfl((int)c2l, srcA, 64);
            const unsigned a1 = __shfl((int)c1l, srcA, 64), a3 = __shfl((int)c3l, srcA, 64);
            const unsigned b0 = __shfl((int)c0l, srcB, 64), b2 = __shfl((int)c2l, srcB, 64);
            const unsigned b1 = __shfl((int)c1l, srcB, 64), b3 = __shfl((int)c3l, srcB, 64);
            const bool lo = (quad < 2);
            pal.u[0] = lo ? a0 : a2; pal.u[1] = lo ? a1 : a3;
            pal.u[2] = lo ? b0 : b2; pal.u[3] = lo ? b1 : b3;
        }

        // PV as O^T: o[dt] holds O[q=lid][d=dt*16+quad*4+r]
        __builtin_amdgcn_s_setprio(1);
#pragma unroll
        for (int dt = 0; dt < 4; dt++) {
            const int d = dt * 16 + lid;
            const int x3 = (dt * 2 + (lid >> 3)) & 3;          // (d>>3) & 3
            const int ro = d * 40 + ((quad ^ x3) << 3);        // de-swizzled b128 read
            const s8v bvh = *(const s8v*)&lVth[ro];
            const s8v bvl = *(const s8v*)&lVtl[ro];
            o[dt] = __builtin_amdgcn_mfma_f32_16x16x32_bf16(bvh, pah.v, o[dt], 0, 0, 0);
            o[dt] = __builtin_amdgcn_mfma_f32_16x16x32_bf16(bvl, pah.v, o[dt], 0, 0, 0);
            o[dt] = __builtin_amdgcn_mfma_f32_16x16x32_bf16(bvh, pal.v, o[dt], 0, 0, 0);
        }
        __builtin_amdgcn_s_setprio(0);
    }
    const float inv_l = 1.0f / l_run;
    const long long obase = (long long)(b * S_ + q0row + lid) * D_ + h * 64 + quad * 4;
#pragma unroll
    for (int dt = 0; dt < 4; dt++) {
        short4 hh4, ll4;
        float v0 = o[dt][0] * inv_l, v1 = o[dt][1] * inv_l;
        float v2 = o[dt][2] * inv_l, v3 = o[dt][3] * inv_l;
        hh4.x = f2bf(v0); ll4.x = f2bf(v0 - b2f(hh4.x));
        hh4.y = f2bf(v1); ll4.y = f2bf(v1 - b2f(hh4.y));
        hh4.z = f2bf(v2); ll4.z = f2bf(v2 - b2f(hh4.z));
        hh4.w = f2bf(v3); ll4.w = f2bf(v3 - b2f(hh4.w));
        *(short4*)&attnh[obase + dt * 16] = hh4;
        *(short4*)&attnl[obase + dt * 16] = ll4;
    }
}

// ---------------- workspace layout (bytes) ----------------
constexpr long long SZ_DD2   = (long long)D_ * D_ * 2;
constexpr long long OFF_WQKVH = 0;
constexpr long long OFF_WQKVL = OFF_WQKVH + 3 * SZ_DD2;
constexpr long long OFF_WOH   = OFF_WQKVL + 3 * SZ_DD2;
constexpr long long OFF_WOL   = OFF_WOH + SZ_DD2;
constexpr long long OFF_W1T   = OFF_WOL + SZ_DD2;
constexpr long long OFF_W2T   = OFF_W1T + (long long)E_ * F_ * D_ * 2;
constexpr long long OFF_WS1T  = OFF_W2T + (long long)E_ * D_ * F_ * 2;
constexpr long long OFF_WS2T  = OFF_WS1T + (long long)FS_ * D_ * 2;
constexpr long long OFF_X1    = OFF_WS2T + (long long)D_ * FS_ * 2;
constexpr long long OFF_XN2   = OFF_X1 + (long long)T_ * D_ * 4;
constexpr long long OFF_TOPI  = OFF_XN2 + (long long)T_ * D_ * 2;
constexpr long long OFF_GATES = OFF_TOPI + (long long)T_ * 2 * 4;
constexpr long long OFF_POSC  = OFF_GATES + (long long)T_ * 2 * 4;
constexpr long long OFF_WVAL  = OFF_POSC + (long long)2 * T_ * 4;
constexpr long long ZONE      = OFF_WVAL + (long long)2 * T_ * 4;
// attention phase
constexpr long long OFF_XH1   = ZONE;
constexpr long long OFF_XL1   = OFF_XH1 + (long long)T_ * D_ * 2;
constexpr long long OFF_QKVH  = OFF_XL1 + (long long)T_ * D_ * 2;
constexpr long long OFF_QKVL  = OFF_QKVH + (long long)T_ * 3 * D_ * 2;
constexpr long long OFF_ATTNH = OFF_QKVL + (long long)T_ * 3 * D_ * 2;
constexpr long long OFF_ATTNL = OFF_ATTNH + (long long)T_ * D_ * 2;
// MoE phase (reuses attention zone)
constexpr long long OFF_DISP  = ZONE;
constexpr long long OFF_H     = OFF_DISP + (long long)E_ * CAP_ * D_ * 2;   // 4-expert H slab
constexpr long long OFF_EO    = OFF_H + (long long)4 * CAP_ * F_ * 2;
constexpr long long OFF_YS    = OFF_EO + (long long)E_ * CAP_ * D_ * 4;
constexpr long long OFF_HS    = ZONE;  // after experts (disp dead)

extern "C" void kernel_launch(void* const* d_in, const int* in_sizes, int n_in,
                              void* d_out, int out_size, void* d_ws, size_t ws_size,
                              hipStream_t stream)
{
    (void)in_sizes; (void)n_in; (void)out_size; (void)ws_size;
    const float* x       = (const float*)d_in[0];
    const unsigned char* mask = (const unsigned char*)d_in[1];
    const float* ln1g    = (const float*)d_in[2];
    const float* ln1b    = (const float*)d_in[3];
    const float* wq      = (const float*)d_in[4];
    const float* bq      = (const float*)d_in[5];
    const float* wk      = (const float*)d_in[6];
    const float* bk      = (const float*)d_in[7];
    const float* wvp     = (const float*)d_in[8];
    const float* bvv     = (const float*)d_in[9];
    const float* wo      = (const float*)d_in[10];
    const float* bo      = (const float*)d_in[11];
    const float* ln2g    = (const float*)d_in[12];
    const float* ln2b    = (const float*)d_in[13];
    const float* wrouter = (const float*)d_in[14];
    const float* w1      = (const float*)d_in[15];
    const float* b1      = (const float*)d_in[16];
    const float* w2      = (const float*)d_in[17];
    const float* b2      = (const float*)d_in[18];
    const float* ws1     = (const float*)d_in[19];
    const float* bs1     = (const float*)d_in[20];
    const float* ws2     = (const float*)d_in[21];
    const float* bs2     = (const float*)d_in[22];
    float* out = (float*)d_out;
    char* ws = (char*)d_ws;

    short* wqkvh = (short*)(ws + OFF_WQKVH);
    short* wqkvl = (short*)(ws + OFF_WQKVL);
    short* woh   = (short*)(ws + OFF_WOH);
    short* wol   = (short*)(ws + OFF_WOL);
    short* w1T   = (short*)(ws + OFF_W1T);
    short* w2T   = (short*)(ws + OFF_W2T);
    short* ws1T  = (short*)(ws + OFF_WS1T);
    short* ws2T  = (short*)(ws + OFF_WS2T);
    float* x1    = (float*)(ws + OFF_X1);
    short* xn2   = (short*)(ws + OFF_XN2);
    int*   topi  = (int*)(ws + OFF_TOPI);
    float* gates = (float*)(ws + OFF_GATES);
    int*   posc  = (int*)(ws + OFF_POSC);
    float* wval  = (float*)(ws + OFF_WVAL);
    short* xh1   = (short*)(ws + OFF_XH1);
    short* xl1   = (short*)(ws + OFF_XL1);
    short* qkvh  = (short*)(ws + OFF_QKVH);
    short* qkvl  = (short*)(ws + OFF_QKVL);
    short* attnh = (short*)(ws + OFF_ATTNH);
    short* attnl = (short*)(ws + OFF_ATTNL);
    short* disp  = (short*)(ws + OFF_DISP);
    short* hbuf  = (short*)(ws + OFF_H);
    float* eo    = (float*)(ws + OFF_EO);
    short* hs    = (short*)(ws + OFF_HS);
    float* ysb   = (float*)(ws + OFF_YS);

    const dim3 tb(256);
    transcvt2<<<dim3(32, 32), tb, 0, stream>>>(wq,  wqkvh,               wqkvl,               1024, 1024);
    transcvt2<<<dim3(32, 32), tb, 0, stream>>>(wk,  wqkvh + 1024 * 1024, wqkvl + 1024 * 1024, 1024, 1024);
    transcvt2<<<dim3(32, 32), tb, 0, stream>>>(wvp, wqkvh + 2 * 1024 * 1024, wqkvl + 2 * 1024 * 1024, 1024, 1024);
    transcvt2<<<dim3(32, 32), tb, 0, stream>>>(wo,  woh, wol, 1024, 1024);
    transcvt<<<dim3(128, 32, 8), tb, 0, stream>>>(w1, w1T, 1024, 4096);
    transcvt<<<dim3(32, 128, 8), tb, 0, stream>>>(w2, w2T, 4096, 1024);
    transcvt<<<dim3(64, 32, 1), tb, 0, stream>>>(ws1, ws1T, 1024, 2048);
    transcvt<<<dim3(32, 64, 1), tb, 0, stream>>>(ws2, ws2T, 2048, 1024);

    ln1_split<<<T_, 256, 0, stream>>>(x, ln1g, ln1b, xh1, xl1);

    // fused QKV: B = [3072,1024] (wq^T|wk^T|wv^T contiguous), per-segment bias
    gemm_hl<0><<<dim3(24, 64), 256, 0, stream>>>(xh1, xl1, wqkvh, wqkvl,
        bq, bk, bvv, nullptr, qkvh, qkvl, nullptr, T_, 3072, 1024, 3072);

    flash_attn_hl<<<dim3(32, 64), 256, 0, stream>>>(qkvh, qkvl, mask, attnh, attnl);

    gemm_hl<1><<<dim3(8, 64), 256, 0, stream>>>(attnh, attnl, woh, wol,
        bo, bo, bo, x, nullptr, nullptr, x1, T_, 1024, 1024, 1024);

    ln2_router_kernel<<<T_, 256, 0, stream>>>(x1, ln2g, ln2b, wrouter, xn2, topi, gates);
    route_scan<<<1, 256, 0, stream>>>(topi, gates, posc, wval);
    dispatch_kernel<<<2 * T_, 128, 0, stream>>>(xn2, topi, posc, disp);

    // experts batched over blockIdx.z in 2 groups of 4 (H slab = 4 experts)
    for (int g = 0; g < 2; g++) {
        const long long e0 = (long long)g * 4;
        gemm_btz<1><<<dim3(32, 20, 4), 256, 0, stream>>>(
            disp + e0 * CAP_ * D_, w1T + e0 * F_ * D_, b1 + e0 * F_, hbuf,
            CAP_, F_, 1024, F_,
            (long long)CAP_ * D_, (long long)F_ * D_, (long long)F_, (long long)CAP_ * F_);
        gemm_btz<2><<<dim3(8, 20, 4), 256, 0, stream>>>(
            hbuf, w2T + e0 * D_ * F_, b2 + e0 * D_, eo + e0 * CAP_ * D_,
            CAP_, 1024, F_, 1024,
            (long long)CAP_ * F_, (long long)D_ * F_, (long long)D_, (long long)CAP_ * D_);
    }

    gemm_btz<1><<<dim3(16, 64, 1), 256, 0, stream>>>(xn2, ws1T, bs1, hs,
        T_, FS_, 1024, FS_, 0, 0, 0, 0);
    gemm_btz<2><<<dim3(8, 64, 1), 256, 0, stream>>>(hs, ws2T, bs2, ysb,
        T_, 1024, FS_, 1024, 0, 0, 0, 0);

    combine_kernel<<<T_, 256, 0, stream>>>(x1, ysb, eo, topi, posc, wval, out);
}